// Round 19
// baseline (921.532 us; speedup 1.0000x reference)
//
#include <hip/hip_runtime.h>

#define TOK 2048
#define DM 2048
#define DI 4096
#define NG 8
#define NN 128
#define PROJ_D 10304
#define PROJ_P 10496
#define CONV_D 6144
#define LSEQ 1024
#define CHUNK 64
#define NCHUNK 16

typedef unsigned short u16;
typedef __attribute__((ext_vector_type(4))) float f32x4;
typedef __attribute__((ext_vector_type(8))) short s16x8;
typedef __attribute__((ext_vector_type(4))) unsigned short u16x4;

__device__ __forceinline__ u16 f2bf(float f) {
  union { float f; unsigned u; } x; x.f = f;
  unsigned r = (x.u + 0x7FFFu + ((x.u >> 16) & 1u)) >> 16;
  return (u16)r;
}
__device__ __forceinline__ float bf2f(u16 u) {
  union { unsigned u; float f; } x; x.u = ((unsigned)u) << 16; return x.f;
}

__device__ __forceinline__ float blockReduceSum256(float s) {
  __shared__ float red[4];
  #pragma unroll
  for (int o = 32; o > 0; o >>= 1) s += __shfl_down(s, o, 64);
  int lane = threadIdx.x & 63, wid = threadIdx.x >> 6;
  if (lane == 0) red[wid] = s;
  __syncthreads();
  return red[0] + red[1] + red[2] + red[3];
}

// ---------- fp32 -> bf16 weight conversion (out_proj weight only now) ----------
__global__ __launch_bounds__(256) void cvt_bf16_pad(const float* __restrict__ src, u16* __restrict__ dst,
                                                    long n_src, long n_dst) {
  long i = ((long)blockIdx.x * 256 + threadIdx.x) * 4;
  if (i >= n_dst) return;
  u16x4 o;
  if (i < n_src) {
    f32x4 v = *(const f32x4*)&src[i];
    o.x = f2bf(v.x); o.y = f2bf(v.y); o.z = f2bf(v.z); o.w = f2bf(v.w);
  } else {
    o.x = 0; o.y = 0; o.z = 0; o.w = 0;
  }
  *(u16x4*)&dst[i] = o;
}

// ---------- h = hs + residual; new_residual = h; x = rmsnorm(h)*w -> bf16 ----------
__global__ __launch_bounds__(256) void addnorm_kernel(const float* __restrict__ hs, const float* __restrict__ res,
        const float* __restrict__ w, float* __restrict__ nres, u16* __restrict__ xbf) {
  int row = blockIdx.x;
  size_t base = (size_t)row * DM;
  int tid = threadIdx.x;
  f32x4 h[2];
  float s = 0.f;
  #pragma unroll
  for (int i = 0; i < 2; i++) {
    int off = i * 1024 + tid * 4;
    f32x4 a = *(const f32x4*)&hs[base + off];
    f32x4 b = *(const f32x4*)&res[base + off];
    f32x4 v = a + b;
    h[i] = v;
    *(f32x4*)&nres[base + off] = v;
    s += v.x * v.x + v.y * v.y + v.z * v.z + v.w * v.w;
  }
  s = blockReduceSum256(s);
  float rs = rsqrtf(s * (1.f / DM) + 1e-5f);
  #pragma unroll
  for (int i = 0; i < 2; i++) {
    int off = i * 1024 + tid * 4;
    f32x4 wv = *(const f32x4*)&w[off];
    f32x4 v = h[i];
    u16x4 o;
    o.x = f2bf(v.x * rs * wv.x);
    o.y = f2bf(v.y * rs * wv.y);
    o.z = f2bf(v.z * rs * wv.z);
    o.w = f2bf(v.w * rs * wv.w);
    *(u16x4*)&xbf[base + off] = o;
  }
}

__device__ __forceinline__ void gld_lds16(const void* g, void* l) {
  __builtin_amdgcn_global_load_lds((const __attribute__((address_space(1))) void*)g,
                                   (__attribute__((address_space(3))) void*)l, 16, 0, 0);
}

// ---------- BK=32 GEMM with FUSED fp32->bf16 B-conversion (in_proj) ----------
// A (bf16 activations): triple-buffered gld_lds, issued 2 tiles ahead.
// B (fp32 weights, read directly): reg-staged 2 tiles ahead (named sets rA/rB,
// kt-pair unrolled), converted+written 1 tile ahead into double-buffered Bs.
// Ledger (per wave, per iter): issue {A(kt+2) gld, B(kt+2) 4xf32x4}; vmcnt(5)
// retires {A(kt+1), B(kt+1)x4} (full-iteration cover); convert+write B(kt+1);
// lgkmcnt(0); barrier; 16 MFMA; barrier. WAR: As[(kt+2)%3] last read at kt-1;
// Bs[(kt+1)&1] last read at kt-1. Padding rows >= PROJ_D: clamped address
// (loads always issued -> uniform vmcnt counting), value zero-selected.
// LDS 56 KB -> 2 blocks/CU. Column-major XCD map (R16/R17).
__global__ __launch_bounds__(512, 4) void gemm32f(const u16* __restrict__ A, const float* __restrict__ Wf,
                                                  u16* __restrict__ C, int K, int Cstride, int nby) {
  __shared__ u16 As[3][128][32];
  __shared__ u16 Bs[2][256][32];
  int tid = threadIdx.x;
  int lane = tid & 63, w = tid >> 6;
  int wr = w >> 2, wc = w & 3;
  int cpx = gridDim.x >> 3;
  int bid = blockIdx.x;
  int lb = (bid & 7) * cpx + (bid >> 3);   // bijective XCD swizzle (grid % 8 == 0)
  int by = lb % nby, bx = lb / nby;        // column-major: XCD owns N-columns
  size_t m0 = (size_t)by * 128, n0 = (size_t)bx * 256;
  const u16* Ab = A + m0 * K;

  f32x4 acc[4][4];
  #pragma unroll
  for (int i = 0; i < 4; ++i)
    #pragma unroll
    for (int j = 0; j < 4; ++j) acc[i][j] = (f32x4){0.f, 0.f, 0.f, 0.f};

  int fr = lane & 15, fq = lane >> 4;
  int lrow = lane >> 2, lg = lane & 3;

  auto SA = [&](int kt) {                  // A tile kt -> As[kt%3] (async)
    int bu = kt % 3;
    int row = w * 16 + lrow;
    int cs = (lg ^ ((row >> 1) & 3)) * 8;
    gld_lds16(Ab + (size_t)row * K + kt * 32 + cs, &As[bu][w * 16][0]);
  };
  auto LB = [&](int kt, f32x4 (&r)[2][2]) {  // issue B(kt) fp32 loads -> regs
    #pragma unroll
    for (int j = 0; j < 2; ++j) {
      int row = j * 128 + w * 16 + lrow;
      long ng = (long)n0 + row;
      long ngc = ng < PROJ_D ? ng : (PROJ_D - 1);   // clamp: always issue loads
      const float* sp = Wf + (size_t)ngc * K + kt * 32 + (lg ^ ((row >> 1) & 3)) * 8;
      r[j][0] = *(const f32x4*)sp;
      r[j][1] = *(const f32x4*)(sp + 4);
    }
  };
  auto CW = [&](int kt, f32x4 (&r)[2][2]) {  // convert + write B(kt) -> Bs[kt&1]
    int d = kt & 1;
    #pragma unroll
    for (int j = 0; j < 2; ++j) {
      int row = j * 128 + w * 16 + lrow;
      bool ok = ((long)n0 + row) < PROJ_D;
      u16x4 o0, o1;
      o0.x = ok ? f2bf(r[j][0].x) : (u16)0;
      o0.y = ok ? f2bf(r[j][0].y) : (u16)0;
      o0.z = ok ? f2bf(r[j][0].z) : (u16)0;
      o0.w = ok ? f2bf(r[j][0].w) : (u16)0;
      o1.x = ok ? f2bf(r[j][1].x) : (u16)0;
      o1.y = ok ? f2bf(r[j][1].y) : (u16)0;
      o1.z = ok ? f2bf(r[j][1].z) : (u16)0;
      o1.w = ok ? f2bf(r[j][1].w) : (u16)0;
      *(u16x4*)&Bs[d][row][lg * 8] = o0;
      *(u16x4*)&Bs[d][row][lg * 8 + 4] = o1;
    }
  };

  int nkt = K >> 5;                         // 64 (even), >= 4
  f32x4 rA[2][2], rB[2][2];
  // prologue: A0,B0,A1,B1 in flight; retire {A0,B0}; convert B0
  SA(0); LB(0, rA);
  SA(1); LB(1, rB);
  asm volatile("s_waitcnt vmcnt(5)" ::: "memory");
  CW(0, rA);
  asm volatile("s_waitcnt lgkmcnt(0)" ::: "memory");
  __builtin_amdgcn_s_barrier();

  auto ITER = [&](int kt, f32x4 (&rload)[2][2], f32x4 (&rconv)[2][2]) {
    int bu = kt % 3, d = kt & 1;
    s16x8 a[4], b[4];
    #pragma unroll
    for (int mi = 0; mi < 4; ++mi) {
      int row = wr * 64 + mi * 16 + fr;
      a[mi] = *(const s16x8*)&As[bu][row][(fq ^ ((row >> 1) & 3)) * 8];
    }
    #pragma unroll
    for (int ni = 0; ni < 4; ++ni) {
      int row = wc * 64 + ni * 16 + fr;
      b[ni] = *(const s16x8*)&Bs[d][row][(fq ^ ((row >> 1) & 3)) * 8];
    }
    if (kt + 2 < nkt) {
      SA(kt + 2); LB(kt + 2, rload);
      asm volatile("s_waitcnt vmcnt(5)" ::: "memory");   // retire A(kt+1)+B(kt+1)
      CW(kt + 1, rconv);
    } else if (kt + 1 < nkt) {
      asm volatile("s_waitcnt vmcnt(0)" ::: "memory");
      CW(kt + 1, rconv);
    } else {
      asm volatile("s_waitcnt vmcnt(0)" ::: "memory");
    }
    asm volatile("s_waitcnt lgkmcnt(0)" ::: "memory");   // B writes visible pre-barrier
    __builtin_amdgcn_s_barrier();
    __builtin_amdgcn_s_setprio(1);
    #pragma unroll
    for (int mi = 0; mi < 4; ++mi)
      #pragma unroll
      for (int ni = 0; ni < 4; ++ni)
        acc[mi][ni] = __builtin_amdgcn_mfma_f32_16x16x32_bf16(a[mi], b[ni], acc[mi][ni], 0, 0, 0);
    __builtin_amdgcn_s_setprio(0);
    __builtin_amdgcn_s_barrier();
  };

  for (int kt = 0; kt < nkt; kt += 2) {
    ITER(kt,     rA, rB);   // load B(kt+2)->rA, convert B(kt+1) from rB
    ITER(kt + 1, rB, rA);   // load B(kt+3)->rB, convert B(kt+2) from rA
  }

  size_t crow0 = m0 + wr * 64 + fq * 4;
  size_t ccol0 = n0 + wc * 64 + fr;
  #pragma unroll
  for (int mi = 0; mi < 4; ++mi)
    #pragma unroll
    for (int ni = 0; ni < 4; ++ni)
      #pragma unroll
      for (int j = 0; j < 4; ++j)
        C[(crow0 + mi * 16 + j) * Cstride + ccol0 + ni * 16] = f2bf(acc[mi][ni][j]);
}

// ---------- 256x256 8-phase bf16 GEMM; K-split; bf16 partials (out_proj) ----------
template <bool KSPLIT>
__global__ __launch_bounds__(512, 2) void gemm8p(const u16* __restrict__ A, const u16* __restrict__ Bw,
                                                 u16* __restrict__ C, int K, int Cstride, int nby,
                                                 int nks, size_t part_stride) {
  __shared__ u16 As[2][256][64];
  __shared__ u16 Bs[2][256][64];
  int tid = threadIdx.x;
  int lane = tid & 63, w = tid >> 6;
  int wr = w >> 2, wc = w & 3;
  int cpx = gridDim.x >> 3;
  int bid = blockIdx.x;
  int lb = (bid & 7) * cpx + (bid >> 3);
  int ks, by, bx;
  if constexpr (KSPLIT) {
    ks = lb % nks;
    int tile = lb / nks;
    by = tile / nby; bx = tile - by * nby;
  } else {
    ks = 0;
    by = lb % nby; bx = lb / nby;
  }
  int Ks = KSPLIT ? (K / nks) : K;
  int k0 = ks * Ks;
  size_t m0 = (size_t)by * 256, n0 = (size_t)bx * 256;
  const u16* Ab = A + m0 * K;
  const u16* Bb = Bw + n0 * K;

  f32x4 acc[8][4];
  #pragma unroll
  for (int i = 0; i < 8; ++i)
    #pragma unroll
    for (int j = 0; j < 4; ++j) acc[i][j] = (f32x4){0.f, 0.f, 0.f, 0.f};

  int l3 = lane >> 3;
  int colsw = ((lane & 7) ^ l3) << 3;
  int fr = lane & 15, fq = lane >> 4;
  int pc0 = (fq * 8) ^ ((fr & 7) << 3);
  int pc1 = pc0 ^ 32;

  auto S = [&](int kt, int mat, int half) {
    int d = kt & 1;
    const u16* src = mat ? Bb : Ab;
    u16* dstbase = mat ? &Bs[d][0][0] : &As[d][0][0];
    #pragma unroll
    for (int j = 0; j < 2; ++j) {
      int rb = half * 128 + (w * 2 + j) * 8;
      gld_lds16(src + (size_t)(rb + l3) * K + k0 + kt * 64 + colsw, dstbase + rb * 64);
    }
  };

  int nkt = Ks >> 6;
  S(0, 1, 0); S(0, 1, 1); S(0, 0, 0); S(0, 0, 1);
  S(1, 1, 0); S(1, 1, 1);
  asm volatile("s_waitcnt vmcnt(4)" ::: "memory");
  __builtin_amdgcn_s_barrier();

  for (int kt = 0; kt < nkt; ++kt) {
    int d = kt & 1;
    s16x8 b[4][2];
    #pragma unroll
    for (int q = 0; q < 4; ++q) {
      if (q == 0) {
        #pragma unroll
        for (int ni = 0; ni < 4; ++ni) {
          b[ni][0] = *(const s16x8*)&Bs[d][wc * 64 + ni * 16 + fr][pc0];
          b[ni][1] = *(const s16x8*)&Bs[d][wc * 64 + ni * 16 + fr][pc1];
        }
      }
      s16x8 a[2][2];
      #pragma unroll
      for (int mi = 0; mi < 2; ++mi) {
        a[mi][0] = *(const s16x8*)&As[d][wr * 128 + q * 32 + mi * 16 + fr][pc0];
        a[mi][1] = *(const s16x8*)&As[d][wr * 128 + q * 32 + mi * 16 + fr][pc1];
      }
      if (q == 0)      { if (kt + 1 < nkt) S(kt + 1, 0, 0); }
      else if (q == 1) { if (kt + 1 < nkt) S(kt + 1, 0, 1); }
      else if (q == 2) { if (kt + 2 < nkt) S(kt + 2, 1, 0); }
      else {
        if (kt + 2 < nkt) { S(kt + 2, 1, 1); asm volatile("s_waitcnt vmcnt(4)" ::: "memory"); }
        else              { asm volatile("s_waitcnt vmcnt(0)" ::: "memory"); }
      }
      __builtin_amdgcn_s_barrier();
      __builtin_amdgcn_s_setprio(1);
      #pragma unroll
      for (int mi = 0; mi < 2; ++mi)
        #pragma unroll
        for (int ni = 0; ni < 4; ++ni) {
          acc[q * 2 + mi][ni] = __builtin_amdgcn_mfma_f32_16x16x32_bf16(a[mi][0], b[ni][0], acc[q * 2 + mi][ni], 0, 0, 0);
          acc[q * 2 + mi][ni] = __builtin_amdgcn_mfma_f32_16x16x32_bf16(a[mi][1], b[ni][1], acc[q * 2 + mi][ni], 0, 0, 0);
        }
      __builtin_amdgcn_s_setprio(0);
      __builtin_amdgcn_s_barrier();
    }
  }
  size_t crow0 = m0 + wr * 128 + fq * 4;
  size_t ccol0 = n0 + wc * 64 + fr;
  u16* Co = KSPLIT ? (C + (size_t)ks * part_stride) : C;
  #pragma unroll
  for (int mf = 0; mf < 8; ++mf)
    #pragma unroll
    for (int ni = 0; ni < 4; ++ni)
      #pragma unroll
      for (int j = 0; j < 4; ++j)
        Co[(crow0 + mf * 16 + j) * Cstride + ccol0 + ni * 16] = f2bf(acc[mf][ni][j]);
}

// ---------- sum 4 bf16 K-split partials (fp32 accumulate) -> fp32 out ----------
__global__ __launch_bounds__(256) void reduce4_kernel(const u16* __restrict__ part, float* __restrict__ out) {
  size_t i = ((size_t)blockIdx.x * 256 + threadIdx.x) * 4;
  const size_t st = (size_t)TOK * DM;
  u16x4 p0 = *(const u16x4*)&part[i];
  u16x4 p1 = *(const u16x4*)&part[i + st];
  u16x4 p2 = *(const u16x4*)&part[i + 2 * st];
  u16x4 p3 = *(const u16x4*)&part[i + 3 * st];
  f32x4 s;
  s.x = bf2f(p0.x) + bf2f(p1.x) + bf2f(p2.x) + bf2f(p3.x);
  s.y = bf2f(p0.y) + bf2f(p1.y) + bf2f(p2.y) + bf2f(p3.y);
  s.z = bf2f(p0.z) + bf2f(p1.z) + bf2f(p2.z) + bf2f(p3.z);
  s.w = bf2f(p0.w) + bf2f(p1.w) + bf2f(p2.w) + bf2f(p3.w);
  *(f32x4*)&out[i] = s;
}

// ---------- causal depthwise conv(K=4) + bias + SiLU, bf16 in -> bf16 out ----------
__global__ __launch_bounds__(256) void conv_silu_kernel(const u16* __restrict__ proj,
        const float* __restrict__ cw, const float* __restrict__ cb, u16* __restrict__ xbc) {
  long gid = (long)blockIdx.x * 256 + threadIdx.x;
  int c4 = (int)(gid % 1536);
  long t = gid / 1536;
  int l = (int)(t & 1023);
  int c = c4 * 4;
  const u16* base = proj + (size_t)t * PROJ_P + DI + c;
  f32x4 acc = *(const f32x4*)&cb[c];
  f32x4 w0 = *(const f32x4*)&cw[(c + 0) * 4];
  f32x4 w1 = *(const f32x4*)&cw[(c + 1) * 4];
  f32x4 w2 = *(const f32x4*)&cw[(c + 2) * 4];
  f32x4 w3 = *(const f32x4*)&cw[(c + 3) * 4];
  #pragma unroll
  for (int k = 0; k < 4; k++) {
    int ls = l - 3 + k;
    if (ls >= 0) {
      u16x4 v = *(const u16x4*)(base + ((long)(k - 3)) * PROJ_P);
      acc.x = fmaf(bf2f(v.x), w0[k], acc.x);
      acc.y = fmaf(bf2f(v.y), w1[k], acc.y);
      acc.z = fmaf(bf2f(v.z), w2[k], acc.z);
      acc.w = fmaf(bf2f(v.w), w3[k], acc.w);
    }
  }
  u16x4 o;
  o.x = f2bf(acc.x / (1.f + expf(-acc.x)));
  o.y = f2bf(acc.y / (1.f + expf(-acc.y)));
  o.z = f2bf(acc.z / (1.f + expf(-acc.z)));
  o.w = f2bf(acc.w / (1.f + expf(-acc.w)));
  *(u16x4*)&xbc[(size_t)t * CONV_D + c] = o;
}

// ---------- dt: softplus(dt+bias) and log-decay dt*A, TRANSPOSED [b*64+h][L] ----------
__global__ __launch_bounds__(256) void dt_kernel(const u16* __restrict__ proj, const float* __restrict__ dt_bias,
        const float* __restrict__ A_log, float* __restrict__ dtspT, float* __restrict__ dtaT) {
  int idx = blockIdx.x * 256 + threadIdx.x;
  int t = idx >> 6, hh = idx & 63;
  int b = t >> 10, l = t & 1023;
  float dtv = bf2f(proj[(size_t)t * PROJ_P + (DI + CONV_D) + hh]) + dt_bias[hh];
  float sp = (dtv > 15.f) ? dtv : log1pf(expf(dtv));
  float Ah = -expf(A_log[hh]);
  size_t o = (size_t)(b * 64 + hh) * LSEQ + l;
  dtspT[o] = sp;
  dtaT[o] = sp * Ah;   // log(dA) exactly
}

// ---------- chunked SSD scan, producer/consumer + p-split (R15, unchanged) ----------
__global__ __launch_bounds__(512) void ssd_kernel(const u16* __restrict__ xbc, const float* __restrict__ dtsp,
        const float* __restrict__ dta, const float* __restrict__ Dp, u16* __restrict__ y) {
  int bid = blockIdx.x;
  int g = bid & 7, b = (bid >> 3) & 1, r = (bid >> 4) & 7, ph = bid >> 7;
  int h = g * 8 + r;
  int p0 = ph * 32;
  int tid = threadIdx.x;
  int w = tid >> 6, lane = tid & 63;

  __shared__ u16 Bsh[2][64][128];
  __shared__ u16 Csh[2][64][128];
  __shared__ u16 Xt[2][32][64];
  __shared__ u16 Btw[2][128][64];
  __shared__ u16 GWsh[64][64];
  __shared__ u16 Hbf[2][32][128];
  __shared__ float dtsh[LSEQ];
  __shared__ float Lsh[LSEQ];

  const float* dtrow = dtsp + (size_t)(b * 64 + h) * LSEQ;
  const float* dtarow = dta + (size_t)(b * 64 + h) * LSEQ;
  if (tid < 256) { f32x4 v = *(const f32x4*)&dtrow[tid * 4]; *(f32x4*)&dtsh[tid * 4] = v; }
  for (int cc = w; cc < NCHUNK; cc += 8) {
    float a = dtarow[cc * 64 + lane];
    #pragma unroll
    for (int o = 1; o < 64; o <<= 1) { float t2 = __shfl_up(a, o, 64); if (lane >= o) a += t2; }
    Lsh[cc * 64 + lane] = a;
  }
  {
    u16* hp = &Hbf[0][0][0];
    for (int i = tid; i < 1024; i += 512) *(u16x4*)&hp[i * 4] = (u16x4){0, 0, 0, 0};
  }
  float Dv = Dp[h];
  const u16* xb = xbc + (size_t)b * LSEQ * CONV_D;
  int swz = (lane & 7) << 3;
  __syncthreads();   // P1: Lsh/dtsh ready

  auto stage = [&](int cc, int d) {
    int t0c = cc * 64;
    int pw = w - 4, ptid = tid - 256;
    #pragma unroll
    for (int q = 0; q < 4; ++q) {
      int rowb = pw * 16 + q * 4;
      int row = rowb + (lane >> 4);
      int colb = ((lane & 15) * 8) ^ ((row & 7) << 3);
      gld_lds16(xb + (size_t)(t0c + row) * CONV_D + DI + g * 128 + colb, &Bsh[d][rowb][0]);
      gld_lds16(xb + (size_t)(t0c + row) * CONV_D + DI + NG * NN + g * 128 + colb, &Csh[d][rowb][0]);
    }
    {
      int s = ptid & 63, pq = ptid >> 6;
      const u16* xr = xb + (size_t)(t0c + s) * CONV_D + g * 512 + r * 64 + p0;
      #pragma unroll
      for (int pb = 0; pb < 2; ++pb) {
        int pl0 = pb * 16 + pq * 4;
        u16x4 v = *(const u16x4*)&xr[pl0];
        #pragma unroll
        for (int j = 0; j < 4; ++j) {
          int p = pl0 + j;
          Xt[d][p][s ^ ((p & 7) << 3)] = v[j];
        }
      }
    }
    {
      int s = ptid & 63, nq = ptid >> 6;
      float wend = __expf(Lsh[t0c + 63] - Lsh[t0c + s]) * dtsh[t0c + s];
      const u16* br = xb + (size_t)(t0c + s) * CONV_D + DI + g * 128;
      #pragma unroll
      for (int nb = 0; nb < 8; ++nb) {
        int n0 = nb * 16 + nq * 4;
        u16x4 v = *(const u16x4*)&br[n0];
        #pragma unroll
        for (int j = 0; j < 4; ++j) {
          int n = n0 + j;
          Btw[d][n][s ^ ((n & 7) << 3)] = f2bf(bf2f(v[j]) * wend);
        }
      }
    }
  };

  if (w >= 4) stage(0, 0);
  __syncthreads();   // P2: chunk 0 staged

  f32x4 hst[2][2];
  #pragma unroll
  for (int i = 0; i < 2; ++i)
    #pragma unroll
    for (int j = 0; j < 2; ++j) hst[i][j] = (f32x4){0.f, 0.f, 0.f, 0.f};

  for (int c = 0; c < NCHUNK; ++c) {
    int d = c & 1;
    int ch = c & 1;
    int t0c = c * 64;
    if (w >= 4) {
      if (c + 1 < NCHUNK) stage(c + 1, d ^ 1);
    } else {
      s16x8 aC[4];
      #pragma unroll
      for (int k = 0; k < 4; ++k)
        aC[k] = *(const s16x8*)&Csh[d][w * 16 + (lane & 15)][(k * 32 + (lane >> 4) * 8) ^ swz];
      f32x4 Gacc[4];
      #pragma unroll
      for (int st = 0; st < 4; ++st) Gacc[st] = (f32x4){0.f, 0.f, 0.f, 0.f};
      #pragma unroll
      for (int st = 0; st < 4; ++st)
        #pragma unroll
        for (int k = 0; k < 4; ++k) {
          s16x8 bB = *(const s16x8*)&Bsh[d][st * 16 + (lane & 15)][(k * 32 + (lane >> 4) * 8) ^ swz];
          Gacc[st] = __builtin_amdgcn_mfma_f32_16x16x32_bf16(aC[k], bB, Gacc[st], 0, 0, 0);
        }
      #pragma unroll
      for (int st = 0; st < 4; ++st) {
        int s = st * 16 + (lane & 15);
        float Ls = Lsh[t0c + s], dts = dtsh[t0c + s];
        #pragma unroll
        for (int j = 0; j < 4; ++j) {
          int t = w * 16 + (lane >> 4) * 4 + j;
          float wgt = (s <= t) ? __expf(Lsh[t0c + t] - Ls) * dts : 0.f;
          GWsh[t][s ^ ((t & 7) << 3)] = f2bf(Gacc[st][j] * wgt);
        }
      }
      f32x4 Yacc[2], Y2acc[2];
      #pragma unroll
      for (int pt = 0; pt < 2; ++pt) { Yacc[pt] = (f32x4){0.f,0.f,0.f,0.f}; Y2acc[pt] = (f32x4){0.f,0.f,0.f,0.f}; }
      s16x8 aGW[2];
      #pragma unroll
      for (int k = 0; k < 2; ++k)
        aGW[k] = *(const s16x8*)&GWsh[w * 16 + (lane & 15)][(k * 32 + (lane >> 4) * 8) ^ swz];
      #pragma unroll
      for (int pt = 0; pt < 2; ++pt) {
        #pragma unroll
        for (int k = 0; k < 2; ++k) {
          s16x8 bX = *(const s16x8*)&Xt[d][pt * 16 + (lane & 15)][(k * 32 + (lane >> 4) * 8) ^ swz];
          Yacc[pt] = __builtin_amdgcn_mfma_f32_16x16x32_bf16(aGW[k], bX, Yacc[pt], 0, 0, 0);
        }
        #pragma unroll
        for (int k = 0; k < 4; ++k) {
          s16x8 bH = *(const s16x8*)&Hbf[ch][pt * 16 + (lane & 15)][(k * 32 + (lane >> 4) * 8) ^ swz];
          Y2acc[pt] = __builtin_amdgcn_mfma_f32_16x16x32_bf16(aC[k], bH, Y2acc[pt], 0, 0, 0);
        }
      }
      float el[4];
      #pragma unroll
      for (int j = 0; j < 4; ++j) el[j] = __expf(Lsh[t0c + w * 16 + (lane >> 4) * 4 + j]);
      #pragma unroll
      for (int pt = 0; pt < 2; ++pt) {
        int p = pt * 16 + (lane & 15);
        #pragma unroll
        for (int j = 0; j < 4; ++j) {
          int t = w * 16 + (lane >> 4) * 4 + j;
          float xv = bf2f(Xt[d][p][t ^ ((p & 7) << 3)]);
          float yv = Yacc[pt][j] + el[j] * Y2acc[pt][j] + Dv * xv;
          y[((size_t)b * LSEQ + t0c + t) * DI + g * 512 + r * 64 + p0 + p] = f2bf(yv);
        }
      }
      float e63 = __expf(Lsh[t0c + 63]);
      s16x8 aX[2][2];
      #pragma unroll
      for (int mp = 0; mp < 2; ++mp)
        #pragma unroll
        for (int k = 0; k < 2; ++k)
          aX[mp][k] = *(const s16x8*)&Xt[d][mp * 16 + (lane & 15)][(k * 32 + (lane >> 4) * 8) ^ swz];
      #pragma unroll
      for (int mp = 0; mp < 2; ++mp)
        #pragma unroll
        for (int nn = 0; nn < 2; ++nn) {
          #pragma unroll
          for (int j = 0; j < 4; ++j) hst[mp][nn][j] *= e63;
          #pragma unroll
          for (int k = 0; k < 2; ++k) {
            s16x8 bW = *(const s16x8*)&Btw[d][w * 32 + nn * 16 + (lane & 15)][(k * 32 + (lane >> 4) * 8) ^ swz];
            hst[mp][nn] = __builtin_amdgcn_mfma_f32_16x16x32_bf16(aX[mp][k], bW, hst[mp][nn], 0, 0, 0);
          }
        }
      #pragma unroll
      for (int mp = 0; mp < 2; ++mp)
        #pragma unroll
        for (int nn = 0; nn < 2; ++nn) {
          int n = w * 32 + nn * 16 + (lane & 15);
          #pragma unroll
          for (int j = 0; j < 4; ++j) {
            int p = mp * 16 + (lane >> 4) * 4 + j;
            Hbf[ch ^ 1][p][n ^ ((p & 7) << 3)] = f2bf(hst[mp][nn][j]);
          }
        }
    }
    __syncthreads();   // single chunk barrier
  }
}

// ---------- y2 = rmsnorm(y * silu(z)) * gw -> bf16 ----------
__global__ __launch_bounds__(256) void gate_kernel(const u16* __restrict__ y, const u16* __restrict__ proj,
        const float* __restrict__ gw, u16* __restrict__ y2) {
  int row = blockIdx.x;
  const u16* yr = y + (size_t)row * DI;
  const u16* zr = proj + (size_t)row * PROJ_P;
  int tid = threadIdx.x;
  f32x4 v[4];
  float s = 0.f;
  #pragma unroll
  for (int i = 0; i < 4; i++) {
    int off = i * 1024 + tid * 4;
    u16x4 av = *(const u16x4*)&yr[off];
    u16x4 zv = *(const u16x4*)&zr[off];
    f32x4 t;
    float z0 = bf2f(zv.x), z1 = bf2f(zv.y), z2 = bf2f(zv.z), z3 = bf2f(zv.w);
    t.x = bf2f(av.x) * (z0 / (1.f + expf(-z0)));
    t.y = bf2f(av.y) * (z1 / (1.f + expf(-z1)));
    t.z = bf2f(av.z) * (z2 / (1.f + expf(-z2)));
    t.w = bf2f(av.w) * (z3 / (1.f + expf(-z3)));
    v[i] = t;
    s += t.x * t.x + t.y * t.y + t.z * t.z + t.w * t.w;
  }
  s = blockReduceSum256(s);
  float rs = rsqrtf(s * (1.f / DI) + 1e-5f);
  #pragma unroll
  for (int i = 0; i < 4; i++) {
    int off = i * 1024 + tid * 4;
    f32x4 wv = *(const f32x4*)&gw[off];
    u16x4 o;
    o.x = f2bf(v[i].x * rs * wv.x);
    o.y = f2bf(v[i].y * rs * wv.y);
    o.z = f2bf(v[i].z * rs * wv.z);
    o.w = f2bf(v[i].w * rs * wv.w);
    *(u16x4*)&y2[(size_t)row * DI + off] = o;
  }
}

extern "C" void kernel_launch(void* const* d_in, const int* in_sizes, int n_in,
                              void* d_out, int out_size, void* d_ws, size_t ws_size,
                              hipStream_t stream) {
  (void)in_sizes; (void)n_in; (void)out_size; (void)ws_size;
  const float* hs      = (const float*)d_in[0];
  const float* res     = (const float*)d_in[1];
  const float* norm_w  = (const float*)d_in[2];
  const float* w_in    = (const float*)d_in[3];
  const float* conv_w  = (const float*)d_in[4];
  const float* conv_b  = (const float*)d_in[5];
  const float* A_log   = (const float*)d_in[6];
  const float* D_param = (const float*)d_in[7];
  const float* dt_bias = (const float*)d_in[8];
  const float* gate_w  = (const float*)d_in[9];
  const float* w_out   = (const float*)d_in[10];

  float* out  = (float*)d_out;
  float* nres = out + (size_t)TOK * DM;

  char* ws = (char*)d_ws;
  size_t off = 0;
  u16*   WB2  = (u16*)(ws + off);   off += (size_t)DM * DI * 2;
  u16*   XBF  = (u16*)(ws + off);   off += (size_t)TOK * DM * 2;
  u16*   PROJ = (u16*)(ws + off);   off += (size_t)TOK * PROJ_P * 2;
  u16*   XBC  = (u16*)(ws + off);   off += (size_t)TOK * CONV_D * 2;
  float* DTSP = (float*)(ws + off); off += (size_t)TOK * 64 * 4;
  float* DTA  = (float*)(ws + off); off += (size_t)TOK * 64 * 4;
  u16*   Y    = (u16*)(ws + off);   off += (size_t)TOK * DI * 2;
  u16*   Y2   = (u16*)(ws + off);   off += (size_t)TOK * DI * 2;
  u16*   PART = (u16*)(ws + off);   off += (size_t)4 * TOK * DM * 2;

  // out_proj weight conversion only (in_proj fused into gemm32f)
  cvt_bf16_pad<<<8192, 256, 0, stream>>>(w_out, WB2, (long)DM * DI, (long)DM * DI);
  // residual add + rmsnorm
  addnorm_kernel<<<TOK, 256, 0, stream>>>(hs, res, norm_w, nres, XBF);
  // in_proj GEMM: fused-convert, BK=32, 2 blocks/CU, column-major map; grid 656
  gemm32f<<<(TOK / 128) * (PROJ_P / 256), 512, 0, stream>>>(XBF, w_in, PROJ, DM, PROJ_P, TOK / 128);
  // conv + silu on xBC slice (bf16 in/out)
  conv_silu_kernel<<<(TOK * (CONV_D / 4)) / 256, 256, 0, stream>>>(PROJ, conv_w, conv_b, XBC);
  // dt softplus + log-decay (transposed layout)
  dt_kernel<<<(TOK * 64) / 256, 256, 0, stream>>>(PROJ, dt_bias, A_log, DTSP, DTA);
  // chunked SSD scan, producer/consumer + p-split, 1 barrier/chunk
  ssd_kernel<<<256, 512, 0, stream>>>(XBC, DTSP, DTA, D_param, Y);
  // gated rmsnorm -> bf16
  gate_kernel<<<TOK, 256, 0, stream>>>(Y, PROJ, gate_w, Y2);
  // out_proj GEMM: 8-phase 256^2, K-split 4 -> bf16 partials
  gemm8p<true><<<(TOK / 256) * (DM / 256) * 4, 512, 0, stream>>>(Y2, WB2, PART, DI, DM, DM / 256, 4, (size_t)TOK * DM);
  // sum partials (fp32 accumulate) -> out
  reduce4_kernel<<<(TOK * DM) / 1024, 256, 0, stream>>>(PART, out);
}

// Round 20
// 282.541 us; speedup vs baseline: 3.2616x; 3.2616x over previous
//
#include <hip/hip_runtime.h>

#define TOK 2048
#define DM 2048
#define DI 4096
#define NG 8
#define NN 128
#define PROJ_D 10304
#define PROJ_P 10496
#define CONV_D 6144
#define LSEQ 1024
#define CHUNK 64
#define NCHUNK 16

typedef unsigned short u16;
typedef __attribute__((ext_vector_type(4))) float f32x4;
typedef __attribute__((ext_vector_type(8))) short s16x8;
typedef __attribute__((ext_vector_type(4))) unsigned short u16x4;

__device__ __forceinline__ u16 f2bf(float f) {
  union { float f; unsigned u; } x; x.f = f;
  unsigned r = (x.u + 0x7FFFu + ((x.u >> 16) & 1u)) >> 16;
  return (u16)r;
}
__device__ __forceinline__ float bf2f(u16 u) {
  union { unsigned u; float f; } x; x.u = ((unsigned)u) << 16; return x.f;
}

__device__ __forceinline__ float blockReduceSum256(float s) {
  __shared__ float red[4];
  #pragma unroll
  for (int o = 32; o > 0; o >>= 1) s += __shfl_down(s, o, 64);
  int lane = threadIdx.x & 63, wid = threadIdx.x >> 6;
  if (lane == 0) red[wid] = s;
  __syncthreads();
  return red[0] + red[1] + red[2] + red[3];
}

// ---------- fp32 -> bf16 weight conversion with zero padding ----------
__global__ __launch_bounds__(256) void cvt_bf16_pad(const float* __restrict__ src, u16* __restrict__ dst,
                                                    long n_src, long n_dst) {
  long i = ((long)blockIdx.x * 256 + threadIdx.x) * 4;
  if (i >= n_dst) return;
  u16x4 o;
  if (i < n_src) {
    f32x4 v = *(const f32x4*)&src[i];
    o.x = f2bf(v.x); o.y = f2bf(v.y); o.z = f2bf(v.z); o.w = f2bf(v.w);
  } else {
    o.x = 0; o.y = 0; o.z = 0; o.w = 0;
  }
  *(u16x4*)&dst[i] = o;
}

// ---------- h = hs + residual; new_residual = h; x = rmsnorm(h)*w -> bf16 ----------
__global__ __launch_bounds__(256) void addnorm_kernel(const float* __restrict__ hs, const float* __restrict__ res,
        const float* __restrict__ w, float* __restrict__ nres, u16* __restrict__ xbf) {
  int row = blockIdx.x;
  size_t base = (size_t)row * DM;
  int tid = threadIdx.x;
  f32x4 h[2];
  float s = 0.f;
  #pragma unroll
  for (int i = 0; i < 2; i++) {
    int off = i * 1024 + tid * 4;
    f32x4 a = *(const f32x4*)&hs[base + off];
    f32x4 b = *(const f32x4*)&res[base + off];
    f32x4 v = a + b;
    h[i] = v;
    *(f32x4*)&nres[base + off] = v;
    s += v.x * v.x + v.y * v.y + v.z * v.z + v.w * v.w;
  }
  s = blockReduceSum256(s);
  float rs = rsqrtf(s * (1.f / DM) + 1e-5f);
  #pragma unroll
  for (int i = 0; i < 2; i++) {
    int off = i * 1024 + tid * 4;
    f32x4 wv = *(const f32x4*)&w[off];
    f32x4 v = h[i];
    u16x4 o;
    o.x = f2bf(v.x * rs * wv.x);
    o.y = f2bf(v.y * rs * wv.y);
    o.z = f2bf(v.z * rs * wv.z);
    o.w = f2bf(v.w * rs * wv.w);
    *(u16x4*)&xbf[base + off] = o;
  }
}

__device__ __forceinline__ void gld_lds16(const void* g, void* l) {
  __builtin_amdgcn_global_load_lds((const __attribute__((address_space(1))) void*)g,
                                   (__attribute__((address_space(3))) void*)l, 16, 0, 0);
}

// ---------- BK=32 triple-buffered GEMM, 2 blocks/CU + COLUMN-MAJOR XCD map (in_proj) ----------
// BM=128, BN=256, 8 waves (2M x 4N, 64x64/wave). LDS 72 KB -> 2 blocks/CU;
// Per K-tile: ONE 16-MFMA phase with vmcnt(3) full-K-tile cover (triple buffer).
// Column-major map: by = lb % 16, bx = lb / 16 -> each XCD owns ~5 N-columns
// (B-slice 5.4 MB, L2-fit), A from L3. Co-resident block fills barrier stalls.
__global__ __launch_bounds__(512, 4) void gemm32(const u16* __restrict__ A, const u16* __restrict__ Bw,
                                                 u16* __restrict__ C, int K, int Cstride, int nby) {
  __shared__ u16 As[3][128][32];
  __shared__ u16 Bs[3][256][32];
  int tid = threadIdx.x;
  int lane = tid & 63, w = tid >> 6;
  int wr = w >> 2, wc = w & 3;
  int cpx = gridDim.x >> 3;
  int bid = blockIdx.x;
  int lb = (bid & 7) * cpx + (bid >> 3);   // bijective XCD swizzle (grid % 8 == 0)
  int by = lb % nby, bx = lb / nby;        // column-major: XCD owns N-columns
  size_t m0 = (size_t)by * 128, n0 = (size_t)bx * 256;
  const u16* Ab = A + m0 * K;
  const u16* Bb = Bw + n0 * K;

  f32x4 acc[4][4];
  #pragma unroll
  for (int i = 0; i < 4; ++i)
    #pragma unroll
    for (int j = 0; j < 4; ++j) acc[i][j] = (f32x4){0.f, 0.f, 0.f, 0.f};

  int fr = lane & 15, fq = lane >> 4;
  int lrow = lane >> 2, lg = lane & 3;     // staging: lane -> (row offset, granule)

  auto S = [&](int kt) {
    int bu = kt % 3;
    {
      int row = w * 16 + lrow;
      int cs = (lg ^ ((row >> 1) & 3)) * 8;
      gld_lds16(Ab + (size_t)row * K + kt * 32 + cs, &As[bu][w * 16][0]);
    }
    #pragma unroll
    for (int j = 0; j < 2; ++j) {
      int row = j * 128 + w * 16 + lrow;
      int cs = (lg ^ ((row >> 1) & 3)) * 8;
      gld_lds16(Bb + (size_t)row * K + kt * 32 + cs, &Bs[bu][j * 128 + w * 16][0]);
    }
  };

  int nkt = K >> 5;                         // requires nkt >= 2
  S(0); S(1);
  asm volatile("s_waitcnt vmcnt(3)" ::: "memory");   // retire kt0, keep kt1 in flight
  __builtin_amdgcn_s_barrier();

  for (int kt = 0; kt < nkt; ++kt) {
    int bu = kt % 3;
    s16x8 a[4], b[4];
    #pragma unroll
    for (int mi = 0; mi < 4; ++mi) {
      int row = wr * 64 + mi * 16 + fr;
      a[mi] = *(const s16x8*)&As[bu][row][(fq ^ ((row >> 1) & 3)) * 8];
    }
    #pragma unroll
    for (int ni = 0; ni < 4; ++ni) {
      int row = wc * 64 + ni * 16 + fr;
      b[ni] = *(const s16x8*)&Bs[bu][row][(fq ^ ((row >> 1) & 3)) * 8];
    }
    if (kt + 2 < nkt) {
      S(kt + 2);
      asm volatile("s_waitcnt vmcnt(3)" ::: "memory");   // retire kt+1, keep kt+2
    } else {
      asm volatile("s_waitcnt vmcnt(0)" ::: "memory");
    }
    __builtin_amdgcn_s_barrier();
    __builtin_amdgcn_s_setprio(1);
    #pragma unroll
    for (int mi = 0; mi < 4; ++mi)
      #pragma unroll
      for (int ni = 0; ni < 4; ++ni)
        acc[mi][ni] = __builtin_amdgcn_mfma_f32_16x16x32_bf16(a[mi], b[ni], acc[mi][ni], 0, 0, 0);
    __builtin_amdgcn_s_setprio(0);
    __builtin_amdgcn_s_barrier();
  }
  size_t crow0 = m0 + wr * 64 + fq * 4;
  size_t ccol0 = n0 + wc * 64 + fr;
  #pragma unroll
  for (int mi = 0; mi < 4; ++mi)
    #pragma unroll
    for (int ni = 0; ni < 4; ++ni)
      #pragma unroll
      for (int j = 0; j < 4; ++j)
        C[(crow0 + mi * 16 + j) * Cstride + ccol0 + ni * 16] = f2bf(acc[mi][ni][j]);
}

// ---------- 256x256 8-phase bf16 GEMM; K-split; bf16 partials (out_proj) ----------
template <bool KSPLIT>
__global__ __launch_bounds__(512, 2) void gemm8p(const u16* __restrict__ A, const u16* __restrict__ Bw,
                                                 u16* __restrict__ C, int K, int Cstride, int nby,
                                                 int nks, size_t part_stride) {
  __shared__ u16 As[2][256][64];
  __shared__ u16 Bs[2][256][64];
  int tid = threadIdx.x;
  int lane = tid & 63, w = tid >> 6;
  int wr = w >> 2, wc = w & 3;
  int cpx = gridDim.x >> 3;
  int bid = blockIdx.x;
  int lb = (bid & 7) * cpx + (bid >> 3);
  int ks, by, bx;
  if constexpr (KSPLIT) {
    ks = lb % nks;
    int tile = lb / nks;
    by = tile / nby; bx = tile - by * nby;
  } else {
    ks = 0;
    by = lb % nby; bx = lb / nby;
  }
  int Ks = KSPLIT ? (K / nks) : K;
  int k0 = ks * Ks;
  size_t m0 = (size_t)by * 256, n0 = (size_t)bx * 256;
  const u16* Ab = A + m0 * K;
  const u16* Bb = Bw + n0 * K;

  f32x4 acc[8][4];
  #pragma unroll
  for (int i = 0; i < 8; ++i)
    #pragma unroll
    for (int j = 0; j < 4; ++j) acc[i][j] = (f32x4){0.f, 0.f, 0.f, 0.f};

  int l3 = lane >> 3;
  int colsw = ((lane & 7) ^ l3) << 3;
  int fr = lane & 15, fq = lane >> 4;
  int pc0 = (fq * 8) ^ ((fr & 7) << 3);
  int pc1 = pc0 ^ 32;

  auto S = [&](int kt, int mat, int half) {
    int d = kt & 1;
    const u16* src = mat ? Bb : Ab;
    u16* dstbase = mat ? &Bs[d][0][0] : &As[d][0][0];
    #pragma unroll
    for (int j = 0; j < 2; ++j) {
      int rb = half * 128 + (w * 2 + j) * 8;
      gld_lds16(src + (size_t)(rb + l3) * K + k0 + kt * 64 + colsw, dstbase + rb * 64);
    }
  };

  int nkt = Ks >> 6;
  S(0, 1, 0); S(0, 1, 1); S(0, 0, 0); S(0, 0, 1);
  S(1, 1, 0); S(1, 1, 1);
  asm volatile("s_waitcnt vmcnt(4)" ::: "memory");
  __builtin_amdgcn_s_barrier();

  for (int kt = 0; kt < nkt; ++kt) {
    int d = kt & 1;
    s16x8 b[4][2];
    #pragma unroll
    for (int q = 0; q < 4; ++q) {
      if (q == 0) {
        #pragma unroll
        for (int ni = 0; ni < 4; ++ni) {
          b[ni][0] = *(const s16x8*)&Bs[d][wc * 64 + ni * 16 + fr][pc0];
          b[ni][1] = *(const s16x8*)&Bs[d][wc * 64 + ni * 16 + fr][pc1];
        }
      }
      s16x8 a[2][2];
      #pragma unroll
      for (int mi = 0; mi < 2; ++mi) {
        a[mi][0] = *(const s16x8*)&As[d][wr * 128 + q * 32 + mi * 16 + fr][pc0];
        a[mi][1] = *(const s16x8*)&As[d][wr * 128 + q * 32 + mi * 16 + fr][pc1];
      }
      if (q == 0)      { if (kt + 1 < nkt) S(kt + 1, 0, 0); }
      else if (q == 1) { if (kt + 1 < nkt) S(kt + 1, 0, 1); }
      else if (q == 2) { if (kt + 2 < nkt) S(kt + 2, 1, 0); }
      else {
        if (kt + 2 < nkt) { S(kt + 2, 1, 1); asm volatile("s_waitcnt vmcnt(4)" ::: "memory"); }
        else              { asm volatile("s_waitcnt vmcnt(0)" ::: "memory"); }
      }
      __builtin_amdgcn_s_barrier();
      __builtin_amdgcn_s_setprio(1);
      #pragma unroll
      for (int mi = 0; mi < 2; ++mi)
        #pragma unroll
        for (int ni = 0; ni < 4; ++ni) {
          acc[q * 2 + mi][ni] = __builtin_amdgcn_mfma_f32_16x16x32_bf16(a[mi][0], b[ni][0], acc[q * 2 + mi][ni], 0, 0, 0);
          acc[q * 2 + mi][ni] = __builtin_amdgcn_mfma_f32_16x16x32_bf16(a[mi][1], b[ni][1], acc[q * 2 + mi][ni], 0, 0, 0);
        }
      __builtin_amdgcn_s_setprio(0);
      __builtin_amdgcn_s_barrier();
    }
  }
  size_t crow0 = m0 + wr * 128 + fq * 4;
  size_t ccol0 = n0 + wc * 64 + fr;
  u16* Co = KSPLIT ? (C + (size_t)ks * part_stride) : C;
  #pragma unroll
  for (int mf = 0; mf < 8; ++mf)
    #pragma unroll
    for (int ni = 0; ni < 4; ++ni)
      #pragma unroll
      for (int j = 0; j < 4; ++j)
        Co[(crow0 + mf * 16 + j) * Cstride + ccol0 + ni * 16] = f2bf(acc[mf][ni][j]);
}

// ---------- sum 4 bf16 K-split partials (fp32 accumulate) -> fp32 out ----------
__global__ __launch_bounds__(256) void reduce4_kernel(const u16* __restrict__ part, float* __restrict__ out) {
  size_t i = ((size_t)blockIdx.x * 256 + threadIdx.x) * 4;
  const size_t st = (size_t)TOK * DM;
  u16x4 p0 = *(const u16x4*)&part[i];
  u16x4 p1 = *(const u16x4*)&part[i + st];
  u16x4 p2 = *(const u16x4*)&part[i + 2 * st];
  u16x4 p3 = *(const u16x4*)&part[i + 3 * st];
  f32x4 s;
  s.x = bf2f(p0.x) + bf2f(p1.x) + bf2f(p2.x) + bf2f(p3.x);
  s.y = bf2f(p0.y) + bf2f(p1.y) + bf2f(p2.y) + bf2f(p3.y);
  s.z = bf2f(p0.z) + bf2f(p1.z) + bf2f(p2.z) + bf2f(p3.z);
  s.w = bf2f(p0.w) + bf2f(p1.w) + bf2f(p2.w) + bf2f(p3.w);
  *(f32x4*)&out[i] = s;
}

// ---------- causal depthwise conv(K=4) + bias + SiLU, bf16 in -> bf16 out ----------
__global__ __launch_bounds__(256) void conv_silu_kernel(const u16* __restrict__ proj,
        const float* __restrict__ cw, const float* __restrict__ cb, u16* __restrict__ xbc) {
  long gid = (long)blockIdx.x * 256 + threadIdx.x;
  int c4 = (int)(gid % 1536);
  long t = gid / 1536;
  int l = (int)(t & 1023);
  int c = c4 * 4;
  const u16* base = proj + (size_t)t * PROJ_P + DI + c;
  f32x4 acc = *(const f32x4*)&cb[c];
  f32x4 w0 = *(const f32x4*)&cw[(c + 0) * 4];
  f32x4 w1 = *(const f32x4*)&cw[(c + 1) * 4];
  f32x4 w2 = *(const f32x4*)&cw[(c + 2) * 4];
  f32x4 w3 = *(const f32x4*)&cw[(c + 3) * 4];
  #pragma unroll
  for (int k = 0; k < 4; k++) {
    int ls = l - 3 + k;
    if (ls >= 0) {
      u16x4 v = *(const u16x4*)(base + ((long)(k - 3)) * PROJ_P);
      acc.x = fmaf(bf2f(v.x), w0[k], acc.x);
      acc.y = fmaf(bf2f(v.y), w1[k], acc.y);
      acc.z = fmaf(bf2f(v.z), w2[k], acc.z);
      acc.w = fmaf(bf2f(v.w), w3[k], acc.w);
    }
  }
  u16x4 o;
  o.x = f2bf(acc.x / (1.f + expf(-acc.x)));
  o.y = f2bf(acc.y / (1.f + expf(-acc.y)));
  o.z = f2bf(acc.z / (1.f + expf(-acc.z)));
  o.w = f2bf(acc.w / (1.f + expf(-acc.w)));
  *(u16x4*)&xbc[(size_t)t * CONV_D + c] = o;
}

// ---------- dt: softplus(dt+bias) and log-decay dt*A, TRANSPOSED [b*64+h][L] ----------
__global__ __launch_bounds__(256) void dt_kernel(const u16* __restrict__ proj, const float* __restrict__ dt_bias,
        const float* __restrict__ A_log, float* __restrict__ dtspT, float* __restrict__ dtaT) {
  int idx = blockIdx.x * 256 + threadIdx.x;
  int t = idx >> 6, hh = idx & 63;
  int b = t >> 10, l = t & 1023;
  float dtv = bf2f(proj[(size_t)t * PROJ_P + (DI + CONV_D) + hh]) + dt_bias[hh];
  float sp = (dtv > 15.f) ? dtv : log1pf(expf(dtv));
  float Ah = -expf(A_log[hh]);
  size_t o = (size_t)(b * 64 + hh) * LSEQ + l;
  dtspT[o] = sp;
  dtaT[o] = sp * Ah;   // log(dA) exactly
}

// ---------- chunked SSD scan, producer/consumer + p-split (R15, unchanged) ----------
__global__ __launch_bounds__(512) void ssd_kernel(const u16* __restrict__ xbc, const float* __restrict__ dtsp,
        const float* __restrict__ dta, const float* __restrict__ Dp, u16* __restrict__ y) {
  int bid = blockIdx.x;
  int g = bid & 7, b = (bid >> 3) & 1, r = (bid >> 4) & 7, ph = bid >> 7;
  int h = g * 8 + r;
  int p0 = ph * 32;
  int tid = threadIdx.x;
  int w = tid >> 6, lane = tid & 63;

  __shared__ u16 Bsh[2][64][128];
  __shared__ u16 Csh[2][64][128];
  __shared__ u16 Xt[2][32][64];
  __shared__ u16 Btw[2][128][64];
  __shared__ u16 GWsh[64][64];
  __shared__ u16 Hbf[2][32][128];
  __shared__ float dtsh[LSEQ];
  __shared__ float Lsh[LSEQ];

  const float* dtrow = dtsp + (size_t)(b * 64 + h) * LSEQ;
  const float* dtarow = dta + (size_t)(b * 64 + h) * LSEQ;
  if (tid < 256) { f32x4 v = *(const f32x4*)&dtrow[tid * 4]; *(f32x4*)&dtsh[tid * 4] = v; }
  for (int cc = w; cc < NCHUNK; cc += 8) {
    float a = dtarow[cc * 64 + lane];
    #pragma unroll
    for (int o = 1; o < 64; o <<= 1) { float t2 = __shfl_up(a, o, 64); if (lane >= o) a += t2; }
    Lsh[cc * 64 + lane] = a;
  }
  {
    u16* hp = &Hbf[0][0][0];
    for (int i = tid; i < 1024; i += 512) *(u16x4*)&hp[i * 4] = (u16x4){0, 0, 0, 0};
  }
  float Dv = Dp[h];
  const u16* xb = xbc + (size_t)b * LSEQ * CONV_D;
  int swz = (lane & 7) << 3;
  __syncthreads();   // P1: Lsh/dtsh ready

  auto stage = [&](int cc, int d) {
    int t0c = cc * 64;
    int pw = w - 4, ptid = tid - 256;
    #pragma unroll
    for (int q = 0; q < 4; ++q) {
      int rowb = pw * 16 + q * 4;
      int row = rowb + (lane >> 4);
      int colb = ((lane & 15) * 8) ^ ((row & 7) << 3);
      gld_lds16(xb + (size_t)(t0c + row) * CONV_D + DI + g * 128 + colb, &Bsh[d][rowb][0]);
      gld_lds16(xb + (size_t)(t0c + row) * CONV_D + DI + NG * NN + g * 128 + colb, &Csh[d][rowb][0]);
    }
    {
      int s = ptid & 63, pq = ptid >> 6;
      const u16* xr = xb + (size_t)(t0c + s) * CONV_D + g * 512 + r * 64 + p0;
      #pragma unroll
      for (int pb = 0; pb < 2; ++pb) {
        int pl0 = pb * 16 + pq * 4;
        u16x4 v = *(const u16x4*)&xr[pl0];
        #pragma unroll
        for (int j = 0; j < 4; ++j) {
          int p = pl0 + j;
          Xt[d][p][s ^ ((p & 7) << 3)] = v[j];
        }
      }
    }
    {
      int s = ptid & 63, nq = ptid >> 6;
      float wend = __expf(Lsh[t0c + 63] - Lsh[t0c + s]) * dtsh[t0c + s];
      const u16* br = xb + (size_t)(t0c + s) * CONV_D + DI + g * 128;
      #pragma unroll
      for (int nb = 0; nb < 8; ++nb) {
        int n0 = nb * 16 + nq * 4;
        u16x4 v = *(const u16x4*)&br[n0];
        #pragma unroll
        for (int j = 0; j < 4; ++j) {
          int n = n0 + j;
          Btw[d][n][s ^ ((n & 7) << 3)] = f2bf(bf2f(v[j]) * wend);
        }
      }
    }
  };

  if (w >= 4) stage(0, 0);
  __syncthreads();   // P2: chunk 0 staged

  f32x4 hst[2][2];
  #pragma unroll
  for (int i = 0; i < 2; ++i)
    #pragma unroll
    for (int j = 0; j < 2; ++j) hst[i][j] = (f32x4){0.f, 0.f, 0.f, 0.f};

  for (int c = 0; c < NCHUNK; ++c) {
    int d = c & 1;
    int ch = c & 1;
    int t0c = c * 64;
    if (w >= 4) {
      if (c + 1 < NCHUNK) stage(c + 1, d ^ 1);
    } else {
      s16x8 aC[4];
      #pragma unroll
      for (int k = 0; k < 4; ++k)
        aC[k] = *(const s16x8*)&Csh[d][w * 16 + (lane & 15)][(k * 32 + (lane >> 4) * 8) ^ swz];
      f32x4 Gacc[4];
      #pragma unroll
      for (int st = 0; st < 4; ++st) Gacc[st] = (f32x4){0.f, 0.f, 0.f, 0.f};
      #pragma unroll
      for (int st = 0; st < 4; ++st)
        #pragma unroll
        for (int k = 0; k < 4; ++k) {
          s16x8 bB = *(const s16x8*)&Bsh[d][st * 16 + (lane & 15)][(k * 32 + (lane >> 4) * 8) ^ swz];
          Gacc[st] = __builtin_amdgcn_mfma_f32_16x16x32_bf16(aC[k], bB, Gacc[st], 0, 0, 0);
        }
      #pragma unroll
      for (int st = 0; st < 4; ++st) {
        int s = st * 16 + (lane & 15);
        float Ls = Lsh[t0c + s], dts = dtsh[t0c + s];
        #pragma unroll
        for (int j = 0; j < 4; ++j) {
          int t = w * 16 + (lane >> 4) * 4 + j;
          float wgt = (s <= t) ? __expf(Lsh[t0c + t] - Ls) * dts : 0.f;
          GWsh[t][s ^ ((t & 7) << 3)] = f2bf(Gacc[st][j] * wgt);
        }
      }
      f32x4 Yacc[2], Y2acc[2];
      #pragma unroll
      for (int pt = 0; pt < 2; ++pt) { Yacc[pt] = (f32x4){0.f,0.f,0.f,0.f}; Y2acc[pt] = (f32x4){0.f,0.f,0.f,0.f}; }
      s16x8 aGW[2];
      #pragma unroll
      for (int k = 0; k < 2; ++k)
        aGW[k] = *(const s16x8*)&GWsh[w * 16 + (lane & 15)][(k * 32 + (lane >> 4) * 8) ^ swz];
      #pragma unroll
      for (int pt = 0; pt < 2; ++pt) {
        #pragma unroll
        for (int k = 0; k < 2; ++k) {
          s16x8 bX = *(const s16x8*)&Xt[d][pt * 16 + (lane & 15)][(k * 32 + (lane >> 4) * 8) ^ swz];
          Yacc[pt] = __builtin_amdgcn_mfma_f32_16x16x32_bf16(aGW[k], bX, Yacc[pt], 0, 0, 0);
        }
        #pragma unroll
        for (int k = 0; k < 4; ++k) {
          s16x8 bH = *(const s16x8*)&Hbf[ch][pt * 16 + (lane & 15)][(k * 32 + (lane >> 4) * 8) ^ swz];
          Y2acc[pt] = __builtin_amdgcn_mfma_f32_16x16x32_bf16(aC[k], bH, Y2acc[pt], 0, 0, 0);
        }
      }
      float el[4];
      #pragma unroll
      for (int j = 0; j < 4; ++j) el[j] = __expf(Lsh[t0c + w * 16 + (lane >> 4) * 4 + j]);
      #pragma unroll
      for (int pt = 0; pt < 2; ++pt) {
        int p = pt * 16 + (lane & 15);
        #pragma unroll
        for (int j = 0; j < 4; ++j) {
          int t = w * 16 + (lane >> 4) * 4 + j;
          float xv = bf2f(Xt[d][p][t ^ ((p & 7) << 3)]);
          float yv = Yacc[pt][j] + el[j] * Y2acc[pt][j] + Dv * xv;
          y[((size_t)b * LSEQ + t0c + t) * DI + g * 512 + r * 64 + p0 + p] = f2bf(yv);
        }
      }
      float e63 = __expf(Lsh[t0c + 63]);
      s16x8 aX[2][2];
      #pragma unroll
      for (int mp = 0; mp < 2; ++mp)
        #pragma unroll
        for (int k = 0; k < 2; ++k)
          aX[mp][k] = *(const s16x8*)&Xt[d][mp * 16 + (lane & 15)][(k * 32 + (lane >> 4) * 8) ^ swz];
      #pragma unroll
      for (int mp = 0; mp < 2; ++mp)
        #pragma unroll
        for (int nn = 0; nn < 2; ++nn) {
          #pragma unroll
          for (int j = 0; j < 4; ++j) hst[mp][nn][j] *= e63;
          #pragma unroll
          for (int k = 0; k < 2; ++k) {
            s16x8 bW = *(const s16x8*)&Btw[d][w * 32 + nn * 16 + (lane & 15)][(k * 32 + (lane >> 4) * 8) ^ swz];
            hst[mp][nn] = __builtin_amdgcn_mfma_f32_16x16x32_bf16(aX[mp][k], bW, hst[mp][nn], 0, 0, 0);
          }
        }
      #pragma unroll
      for (int mp = 0; mp < 2; ++mp)
        #pragma unroll
        for (int nn = 0; nn < 2; ++nn) {
          int n = w * 32 + nn * 16 + (lane & 15);
          #pragma unroll
          for (int j = 0; j < 4; ++j) {
            int p = mp * 16 + (lane >> 4) * 4 + j;
            Hbf[ch ^ 1][p][n ^ ((p & 7) << 3)] = f2bf(hst[mp][nn][j]);
          }
        }
    }
    __syncthreads();   // single chunk barrier
  }
}

// ---------- y2 = rmsnorm(y * silu(z)) * gw -> bf16 ----------
__global__ __launch_bounds__(256) void gate_kernel(const u16* __restrict__ y, const u16* __restrict__ proj,
        const float* __restrict__ gw, u16* __restrict__ y2) {
  int row = blockIdx.x;
  const u16* yr = y + (size_t)row * DI;
  const u16* zr = proj + (size_t)row * PROJ_P;
  int tid = threadIdx.x;
  f32x4 v[4];
  float s = 0.f;
  #pragma unroll
  for (int i = 0; i < 4; i++) {
    int off = i * 1024 + tid * 4;
    u16x4 av = *(const u16x4*)&yr[off];
    u16x4 zv = *(const u16x4*)&zr[off];
    f32x4 t;
    float z0 = bf2f(zv.x), z1 = bf2f(zv.y), z2 = bf2f(zv.z), z3 = bf2f(zv.w);
    t.x = bf2f(av.x) * (z0 / (1.f + expf(-z0)));
    t.y = bf2f(av.y) * (z1 / (1.f + expf(-z1)));
    t.z = bf2f(av.z) * (z2 / (1.f + expf(-z2)));
    t.w = bf2f(av.w) * (z3 / (1.f + expf(-z3)));
    v[i] = t;
    s += t.x * t.x + t.y * t.y + t.z * t.z + t.w * t.w;
  }
  s = blockReduceSum256(s);
  float rs = rsqrtf(s * (1.f / DI) + 1e-5f);
  #pragma unroll
  for (int i = 0; i < 4; i++) {
    int off = i * 1024 + tid * 4;
    f32x4 wv = *(const f32x4*)&gw[off];
    u16x4 o;
    o.x = f2bf(v[i].x * rs * wv.x);
    o.y = f2bf(v[i].y * rs * wv.y);
    o.z = f2bf(v[i].z * rs * wv.z);
    o.w = f2bf(v[i].w * rs * wv.w);
    *(u16x4*)&y2[(size_t)row * DI + off] = o;
  }
}

extern "C" void kernel_launch(void* const* d_in, const int* in_sizes, int n_in,
                              void* d_out, int out_size, void* d_ws, size_t ws_size,
                              hipStream_t stream) {
  (void)in_sizes; (void)n_in; (void)out_size; (void)ws_size;
  const float* hs      = (const float*)d_in[0];
  const float* res     = (const float*)d_in[1];
  const float* norm_w  = (const float*)d_in[2];
  const float* w_in    = (const float*)d_in[3];
  const float* conv_w  = (const float*)d_in[4];
  const float* conv_b  = (const float*)d_in[5];
  const float* A_log   = (const float*)d_in[6];
  const float* D_param = (const float*)d_in[7];
  const float* dt_bias = (const float*)d_in[8];
  const float* gate_w  = (const float*)d_in[9];
  const float* w_out   = (const float*)d_in[10];

  float* out  = (float*)d_out;
  float* nres = out + (size_t)TOK * DM;

  char* ws = (char*)d_ws;
  size_t off = 0;
  u16*   WB1  = (u16*)(ws + off);   off += (size_t)PROJ_P * DM * 2;
  u16*   WB2  = (u16*)(ws + off);   off += (size_t)DM * DI * 2;
  u16*   XBF  = (u16*)(ws + off);   off += (size_t)TOK * DM * 2;
  u16*   PROJ = (u16*)(ws + off);   off += (size_t)TOK * PROJ_P * 2;
  u16*   XBC  = (u16*)(ws + off);   off += (size_t)TOK * CONV_D * 2;
  float* DTSP = (float*)(ws + off); off += (size_t)TOK * 64 * 4;
  float* DTA  = (float*)(ws + off); off += (size_t)TOK * 64 * 4;
  u16*   Y    = (u16*)(ws + off);   off += (size_t)TOK * DI * 2;
  u16*   Y2   = (u16*)(ws + off);   off += (size_t)TOK * DI * 2;
  u16*   PART = (u16*)(ws + off);   off += (size_t)4 * TOK * DM * 2;

  // weight conversions
  cvt_bf16_pad<<<20992, 256, 0, stream>>>(w_in, WB1, (long)PROJ_D * DM, (long)PROJ_P * DM);
  cvt_bf16_pad<<<8192, 256, 0, stream>>>(w_out, WB2, (long)DM * DI, (long)DM * DI);
  // residual add + rmsnorm
  addnorm_kernel<<<TOK, 256, 0, stream>>>(hs, res, norm_w, nres, XBF);
  // in_proj GEMM: BK=32 triple-buffered, 2 blocks/CU, column-major map; grid 656 = 8x82
  gemm32<<<(TOK / 128) * (PROJ_P / 256), 512, 0, stream>>>(XBF, WB1, PROJ, DM, PROJ_P, TOK / 128);
  // conv + silu on xBC slice (bf16 in/out)
  conv_silu_kernel<<<(TOK * (CONV_D / 4)) / 256, 256, 0, stream>>>(PROJ, conv_w, conv_b, XBC);
  // dt softplus + log-decay (transposed layout)
  dt_kernel<<<(TOK * 64) / 256, 256, 0, stream>>>(PROJ, dt_bias, A_log, DTSP, DTA);
  // chunked SSD scan, producer/consumer + p-split, 1 barrier/chunk
  ssd_kernel<<<256, 512, 0, stream>>>(XBC, DTSP, DTA, D_param, Y);
  // gated rmsnorm -> bf16
  gate_kernel<<<TOK, 256, 0, stream>>>(Y, PROJ, gate_w, Y2);
  // out_proj GEMM: 8-phase 256^2, K-split 4 -> bf16 partials
  gemm8p<true><<<(TOK / 256) * (DM / 256) * 4, 512, 0, stream>>>(Y2, WB2, PART, DI, DM, DM / 256, 4, (size_t)TOK * DM);
  // sum partials (fp32 accumulate) -> out
  reduce4_kernel<<<(TOK * DM) / 1024, 256, 0, stream>>>(PART, out);
}

// Round 21
// 275.126 us; speedup vs baseline: 3.3495x; 1.0270x over previous
//
#include <hip/hip_runtime.h>

#define TOK 2048
#define DM 2048
#define DI 4096
#define NG 8
#define NN 128
#define PROJ_D 10304
#define PROJ_P 10496
#define CONV_D 6144
#define LSEQ 1024
#define CHUNK 64
#define NCHUNK 16

typedef unsigned short u16;
typedef __attribute__((ext_vector_type(4))) float f32x4;
typedef __attribute__((ext_vector_type(8))) short s16x8;
typedef __attribute__((ext_vector_type(4))) unsigned short u16x4;

__device__ __forceinline__ u16 f2bf(float f) {
  union { float f; unsigned u; } x; x.f = f;
  unsigned r = (x.u + 0x7FFFu + ((x.u >> 16) & 1u)) >> 16;
  return (u16)r;
}
__device__ __forceinline__ float bf2f(u16 u) {
  union { unsigned u; float f; } x; x.u = ((unsigned)u) << 16; return x.f;
}

__device__ __forceinline__ float blockReduceSum256(float s) {
  __shared__ float red[4];
  #pragma unroll
  for (int o = 32; o > 0; o >>= 1) s += __shfl_down(s, o, 64);
  int lane = threadIdx.x & 63, wid = threadIdx.x >> 6;
  if (lane == 0) red[wid] = s;
  __syncthreads();
  return red[0] + red[1] + red[2] + red[3];
}

// ---------- BOTH weight conversions in one launch (block-granular branch) ----------
#define CVT1_BLOCKS 20992   // PROJ_P*DM/1024
#define CVT2_BLOCKS 8192    // DM*DI/1024
__global__ __launch_bounds__(256) void cvt2_kernel(const float* __restrict__ w1, u16* __restrict__ d1,
                                                   const float* __restrict__ w2, u16* __restrict__ d2) {
  long bid = blockIdx.x;
  const float* src; u16* dst; long n_src, i;
  if (bid < CVT1_BLOCKS) {
    i = (bid * 256 + threadIdx.x) * 4;
    src = w1; dst = d1; n_src = (long)PROJ_D * DM;
  } else {
    i = ((bid - CVT1_BLOCKS) * 256 + threadIdx.x) * 4;
    src = w2; dst = d2; n_src = (long)DM * DI;
  }
  u16x4 o;
  if (i < n_src) {
    f32x4 v = *(const f32x4*)&src[i];
    o.x = f2bf(v.x); o.y = f2bf(v.y); o.z = f2bf(v.z); o.w = f2bf(v.w);
  } else {
    o.x = 0; o.y = 0; o.z = 0; o.w = 0;
  }
  *(u16x4*)&dst[i] = o;
}

// ---------- h = hs + residual; new_residual = h; x = rmsnorm(h)*w -> bf16 ----------
__global__ __launch_bounds__(256) void addnorm_kernel(const float* __restrict__ hs, const float* __restrict__ res,
        const float* __restrict__ w, float* __restrict__ nres, u16* __restrict__ xbf) {
  int row = blockIdx.x;
  size_t base = (size_t)row * DM;
  int tid = threadIdx.x;
  f32x4 h[2];
  float s = 0.f;
  #pragma unroll
  for (int i = 0; i < 2; i++) {
    int off = i * 1024 + tid * 4;
    f32x4 a = *(const f32x4*)&hs[base + off];
    f32x4 b = *(const f32x4*)&res[base + off];
    f32x4 v = a + b;
    h[i] = v;
    *(f32x4*)&nres[base + off] = v;
    s += v.x * v.x + v.y * v.y + v.z * v.z + v.w * v.w;
  }
  s = blockReduceSum256(s);
  float rs = rsqrtf(s * (1.f / DM) + 1e-5f);
  #pragma unroll
  for (int i = 0; i < 2; i++) {
    int off = i * 1024 + tid * 4;
    f32x4 wv = *(const f32x4*)&w[off];
    f32x4 v = h[i];
    u16x4 o;
    o.x = f2bf(v.x * rs * wv.x);
    o.y = f2bf(v.y * rs * wv.y);
    o.z = f2bf(v.z * rs * wv.z);
    o.w = f2bf(v.w * rs * wv.w);
    *(u16x4*)&xbf[base + off] = o;
  }
}

__device__ __forceinline__ void gld_lds16(const void* g, void* l) {
  __builtin_amdgcn_global_load_lds((const __attribute__((address_space(1))) void*)g,
                                   (__attribute__((address_space(3))) void*)l, 16, 0, 0);
}

// ---------- BK=32 triple-buffered GEMM, 2 blocks/CU + COLUMN-MAJOR XCD map (in_proj) ----------
// BM=128, BN=256, 8 waves (2M x 4N, 64x64/wave). LDS 72 KB -> 2 blocks/CU;
// Per K-tile: ONE 16-MFMA phase with vmcnt(3) full-K-tile cover (triple buffer).
// Column-major map: by = lb % 16, bx = lb / 16 -> each XCD owns ~5 N-columns
// (B-slice 5.4 MB, L2-fit), A from L3. Co-resident block fills barrier stalls.
__global__ __launch_bounds__(512, 4) void gemm32(const u16* __restrict__ A, const u16* __restrict__ Bw,
                                                 u16* __restrict__ C, int K, int Cstride, int nby) {
  __shared__ u16 As[3][128][32];
  __shared__ u16 Bs[3][256][32];
  int tid = threadIdx.x;
  int lane = tid & 63, w = tid >> 6;
  int wr = w >> 2, wc = w & 3;
  int cpx = gridDim.x >> 3;
  int bid = blockIdx.x;
  int lb = (bid & 7) * cpx + (bid >> 3);   // bijective XCD swizzle (grid % 8 == 0)
  int by = lb % nby, bx = lb / nby;        // column-major: XCD owns N-columns
  size_t m0 = (size_t)by * 128, n0 = (size_t)bx * 256;
  const u16* Ab = A + m0 * K;
  const u16* Bb = Bw + n0 * K;

  f32x4 acc[4][4];
  #pragma unroll
  for (int i = 0; i < 4; ++i)
    #pragma unroll
    for (int j = 0; j < 4; ++j) acc[i][j] = (f32x4){0.f, 0.f, 0.f, 0.f};

  int fr = lane & 15, fq = lane >> 4;
  int lrow = lane >> 2, lg = lane & 3;     // staging: lane -> (row offset, granule)

  auto S = [&](int kt) {
    int bu = kt % 3;
    {
      int row = w * 16 + lrow;
      int cs = (lg ^ ((row >> 1) & 3)) * 8;
      gld_lds16(Ab + (size_t)row * K + kt * 32 + cs, &As[bu][w * 16][0]);
    }
    #pragma unroll
    for (int j = 0; j < 2; ++j) {
      int row = j * 128 + w * 16 + lrow;
      int cs = (lg ^ ((row >> 1) & 3)) * 8;
      gld_lds16(Bb + (size_t)row * K + kt * 32 + cs, &Bs[bu][j * 128 + w * 16][0]);
    }
  };

  int nkt = K >> 5;                         // requires nkt >= 2
  S(0); S(1);
  asm volatile("s_waitcnt vmcnt(3)" ::: "memory");   // retire kt0, keep kt1 in flight
  __builtin_amdgcn_s_barrier();

  for (int kt = 0; kt < nkt; ++kt) {
    int bu = kt % 3;
    s16x8 a[4], b[4];
    #pragma unroll
    for (int mi = 0; mi < 4; ++mi) {
      int row = wr * 64 + mi * 16 + fr;
      a[mi] = *(const s16x8*)&As[bu][row][(fq ^ ((row >> 1) & 3)) * 8];
    }
    #pragma unroll
    for (int ni = 0; ni < 4; ++ni) {
      int row = wc * 64 + ni * 16 + fr;
      b[ni] = *(const s16x8*)&Bs[bu][row][(fq ^ ((row >> 1) & 3)) * 8];
    }
    if (kt + 2 < nkt) {
      S(kt + 2);
      asm volatile("s_waitcnt vmcnt(3)" ::: "memory");   // retire kt+1, keep kt+2
    } else {
      asm volatile("s_waitcnt vmcnt(0)" ::: "memory");
    }
    __builtin_amdgcn_s_barrier();
    __builtin_amdgcn_s_setprio(1);
    #pragma unroll
    for (int mi = 0; mi < 4; ++mi)
      #pragma unroll
      for (int ni = 0; ni < 4; ++ni)
        acc[mi][ni] = __builtin_amdgcn_mfma_f32_16x16x32_bf16(a[mi], b[ni], acc[mi][ni], 0, 0, 0);
    __builtin_amdgcn_s_setprio(0);
    __builtin_amdgcn_s_barrier();
  }
  size_t crow0 = m0 + wr * 64 + fq * 4;
  size_t ccol0 = n0 + wc * 64 + fr;
  #pragma unroll
  for (int mi = 0; mi < 4; ++mi)
    #pragma unroll
    for (int ni = 0; ni < 4; ++ni)
      #pragma unroll
      for (int j = 0; j < 4; ++j)
        C[(crow0 + mi * 16 + j) * Cstride + ccol0 + ni * 16] = f2bf(acc[mi][ni][j]);
}

// ---------- 256x256 8-phase bf16 GEMM; K-split; bf16 partials (out_proj) ----------
template <bool KSPLIT>
__global__ __launch_bounds__(512, 2) void gemm8p(const u16* __restrict__ A, const u16* __restrict__ Bw,
                                                 u16* __restrict__ C, int K, int Cstride, int nby,
                                                 int nks, size_t part_stride) {
  __shared__ u16 As[2][256][64];
  __shared__ u16 Bs[2][256][64];
  int tid = threadIdx.x;
  int lane = tid & 63, w = tid >> 6;
  int wr = w >> 2, wc = w & 3;
  int cpx = gridDim.x >> 3;
  int bid = blockIdx.x;
  int lb = (bid & 7) * cpx + (bid >> 3);
  int ks, by, bx;
  if constexpr (KSPLIT) {
    ks = lb % nks;
    int tile = lb / nks;
    by = tile / nby; bx = tile - by * nby;
  } else {
    ks = 0;
    by = lb % nby; bx = lb / nby;
  }
  int Ks = KSPLIT ? (K / nks) : K;
  int k0 = ks * Ks;
  size_t m0 = (size_t)by * 256, n0 = (size_t)bx * 256;
  const u16* Ab = A + m0 * K;
  const u16* Bb = Bw + n0 * K;

  f32x4 acc[8][4];
  #pragma unroll
  for (int i = 0; i < 8; ++i)
    #pragma unroll
    for (int j = 0; j < 4; ++j) acc[i][j] = (f32x4){0.f, 0.f, 0.f, 0.f};

  int l3 = lane >> 3;
  int colsw = ((lane & 7) ^ l3) << 3;
  int fr = lane & 15, fq = lane >> 4;
  int pc0 = (fq * 8) ^ ((fr & 7) << 3);
  int pc1 = pc0 ^ 32;

  auto S = [&](int kt, int mat, int half) {
    int d = kt & 1;
    const u16* src = mat ? Bb : Ab;
    u16* dstbase = mat ? &Bs[d][0][0] : &As[d][0][0];
    #pragma unroll
    for (int j = 0; j < 2; ++j) {
      int rb = half * 128 + (w * 2 + j) * 8;
      gld_lds16(src + (size_t)(rb + l3) * K + k0 + kt * 64 + colsw, dstbase + rb * 64);
    }
  };

  int nkt = Ks >> 6;
  S(0, 1, 0); S(0, 1, 1); S(0, 0, 0); S(0, 0, 1);
  S(1, 1, 0); S(1, 1, 1);
  asm volatile("s_waitcnt vmcnt(4)" ::: "memory");
  __builtin_amdgcn_s_barrier();

  for (int kt = 0; kt < nkt; ++kt) {
    int d = kt & 1;
    s16x8 b[4][2];
    #pragma unroll
    for (int q = 0; q < 4; ++q) {
      if (q == 0) {
        #pragma unroll
        for (int ni = 0; ni < 4; ++ni) {
          b[ni][0] = *(const s16x8*)&Bs[d][wc * 64 + ni * 16 + fr][pc0];
          b[ni][1] = *(const s16x8*)&Bs[d][wc * 64 + ni * 16 + fr][pc1];
        }
      }
      s16x8 a[2][2];
      #pragma unroll
      for (int mi = 0; mi < 2; ++mi) {
        a[mi][0] = *(const s16x8*)&As[d][wr * 128 + q * 32 + mi * 16 + fr][pc0];
        a[mi][1] = *(const s16x8*)&As[d][wr * 128 + q * 32 + mi * 16 + fr][pc1];
      }
      if (q == 0)      { if (kt + 1 < nkt) S(kt + 1, 0, 0); }
      else if (q == 1) { if (kt + 1 < nkt) S(kt + 1, 0, 1); }
      else if (q == 2) { if (kt + 2 < nkt) S(kt + 2, 1, 0); }
      else {
        if (kt + 2 < nkt) { S(kt + 2, 1, 1); asm volatile("s_waitcnt vmcnt(4)" ::: "memory"); }
        else              { asm volatile("s_waitcnt vmcnt(0)" ::: "memory"); }
      }
      __builtin_amdgcn_s_barrier();
      __builtin_amdgcn_s_setprio(1);
      #pragma unroll
      for (int mi = 0; mi < 2; ++mi)
        #pragma unroll
        for (int ni = 0; ni < 4; ++ni) {
          acc[q * 2 + mi][ni] = __builtin_amdgcn_mfma_f32_16x16x32_bf16(a[mi][0], b[ni][0], acc[q * 2 + mi][ni], 0, 0, 0);
          acc[q * 2 + mi][ni] = __builtin_amdgcn_mfma_f32_16x16x32_bf16(a[mi][1], b[ni][1], acc[q * 2 + mi][ni], 0, 0, 0);
        }
      __builtin_amdgcn_s_setprio(0);
      __builtin_amdgcn_s_barrier();
    }
  }
  size_t crow0 = m0 + wr * 128 + fq * 4;
  size_t ccol0 = n0 + wc * 64 + fr;
  u16* Co = KSPLIT ? (C + (size_t)ks * part_stride) : C;
  #pragma unroll
  for (int mf = 0; mf < 8; ++mf)
    #pragma unroll
    for (int ni = 0; ni < 4; ++ni)
      #pragma unroll
      for (int j = 0; j < 4; ++j)
        Co[(crow0 + mf * 16 + j) * Cstride + ccol0 + ni * 16] = f2bf(acc[mf][ni][j]);
}

// ---------- sum 4 bf16 K-split partials (fp32 accumulate) -> fp32 out ----------
__global__ __launch_bounds__(256) void reduce4_kernel(const u16* __restrict__ part, float* __restrict__ out) {
  size_t i = ((size_t)blockIdx.x * 256 + threadIdx.x) * 4;
  const size_t st = (size_t)TOK * DM;
  u16x4 p0 = *(const u16x4*)&part[i];
  u16x4 p1 = *(const u16x4*)&part[i + st];
  u16x4 p2 = *(const u16x4*)&part[i + 2 * st];
  u16x4 p3 = *(const u16x4*)&part[i + 3 * st];
  f32x4 s;
  s.x = bf2f(p0.x) + bf2f(p1.x) + bf2f(p2.x) + bf2f(p3.x);
  s.y = bf2f(p0.y) + bf2f(p1.y) + bf2f(p2.y) + bf2f(p3.y);
  s.z = bf2f(p0.z) + bf2f(p1.z) + bf2f(p2.z) + bf2f(p3.z);
  s.w = bf2f(p0.w) + bf2f(p1.w) + bf2f(p2.w) + bf2f(p3.w);
  *(f32x4*)&out[i] = s;
}

// ---------- FUSED: causal depthwise conv(K=4)+SiLU (blocks < 12288) | dt softplus/log-decay ----------
#define CONV_BLOCKS 12288   // TOK*1536/256
__global__ __launch_bounds__(256) void conv_dt_kernel(const u16* __restrict__ proj,
        const float* __restrict__ cw, const float* __restrict__ cb, u16* __restrict__ xbc,
        const float* __restrict__ dt_bias, const float* __restrict__ A_log,
        float* __restrict__ dtspT, float* __restrict__ dtaT) {
  long bid = blockIdx.x;
  if (bid < CONV_BLOCKS) {
    long gid = bid * 256 + threadIdx.x;
    int c4 = (int)(gid % 1536);
    long t = gid / 1536;
    int l = (int)(t & 1023);
    int c = c4 * 4;
    const u16* base = proj + (size_t)t * PROJ_P + DI + c;
    f32x4 acc = *(const f32x4*)&cb[c];
    f32x4 w0 = *(const f32x4*)&cw[(c + 0) * 4];
    f32x4 w1 = *(const f32x4*)&cw[(c + 1) * 4];
    f32x4 w2 = *(const f32x4*)&cw[(c + 2) * 4];
    f32x4 w3 = *(const f32x4*)&cw[(c + 3) * 4];
    #pragma unroll
    for (int k = 0; k < 4; k++) {
      int ls = l - 3 + k;
      if (ls >= 0) {
        u16x4 v = *(const u16x4*)(base + ((long)(k - 3)) * PROJ_P);
        acc.x = fmaf(bf2f(v.x), w0[k], acc.x);
        acc.y = fmaf(bf2f(v.y), w1[k], acc.y);
        acc.z = fmaf(bf2f(v.z), w2[k], acc.z);
        acc.w = fmaf(bf2f(v.w), w3[k], acc.w);
      }
    }
    u16x4 o;
    o.x = f2bf(acc.x / (1.f + expf(-acc.x)));
    o.y = f2bf(acc.y / (1.f + expf(-acc.y)));
    o.z = f2bf(acc.z / (1.f + expf(-acc.z)));
    o.w = f2bf(acc.w / (1.f + expf(-acc.w)));
    *(u16x4*)&xbc[(size_t)t * CONV_D + c] = o;
  } else {
    int idx = (int)(bid - CONV_BLOCKS) * 256 + threadIdx.x;
    int t = idx >> 6, hh = idx & 63;
    int b = t >> 10, l = t & 1023;
    float dtv = bf2f(proj[(size_t)t * PROJ_P + (DI + CONV_D) + hh]) + dt_bias[hh];
    float sp = (dtv > 15.f) ? dtv : log1pf(expf(dtv));
    float Ah = -expf(A_log[hh]);
    size_t o = (size_t)(b * 64 + hh) * LSEQ + l;
    dtspT[o] = sp;
    dtaT[o] = sp * Ah;   // log(dA) exactly
  }
}

// ---------- chunked SSD scan, producer/consumer + p-split (R15, unchanged) ----------
__global__ __launch_bounds__(512) void ssd_kernel(const u16* __restrict__ xbc, const float* __restrict__ dtsp,
        const float* __restrict__ dta, const float* __restrict__ Dp, u16* __restrict__ y) {
  int bid = blockIdx.x;
  int g = bid & 7, b = (bid >> 3) & 1, r = (bid >> 4) & 7, ph = bid >> 7;
  int h = g * 8 + r;
  int p0 = ph * 32;
  int tid = threadIdx.x;
  int w = tid >> 6, lane = tid & 63;

  __shared__ u16 Bsh[2][64][128];
  __shared__ u16 Csh[2][64][128];
  __shared__ u16 Xt[2][32][64];
  __shared__ u16 Btw[2][128][64];
  __shared__ u16 GWsh[64][64];
  __shared__ u16 Hbf[2][32][128];
  __shared__ float dtsh[LSEQ];
  __shared__ float Lsh[LSEQ];

  const float* dtrow = dtsp + (size_t)(b * 64 + h) * LSEQ;
  const float* dtarow = dta + (size_t)(b * 64 + h) * LSEQ;
  if (tid < 256) { f32x4 v = *(const f32x4*)&dtrow[tid * 4]; *(f32x4*)&dtsh[tid * 4] = v; }
  for (int cc = w; cc < NCHUNK; cc += 8) {
    float a = dtarow[cc * 64 + lane];
    #pragma unroll
    for (int o = 1; o < 64; o <<= 1) { float t2 = __shfl_up(a, o, 64); if (lane >= o) a += t2; }
    Lsh[cc * 64 + lane] = a;
  }
  {
    u16* hp = &Hbf[0][0][0];
    for (int i = tid; i < 1024; i += 512) *(u16x4*)&hp[i * 4] = (u16x4){0, 0, 0, 0};
  }
  float Dv = Dp[h];
  const u16* xb = xbc + (size_t)b * LSEQ * CONV_D;
  int swz = (lane & 7) << 3;
  __syncthreads();   // P1: Lsh/dtsh ready

  auto stage = [&](int cc, int d) {
    int t0c = cc * 64;
    int pw = w - 4, ptid = tid - 256;
    #pragma unroll
    for (int q = 0; q < 4; ++q) {
      int rowb = pw * 16 + q * 4;
      int row = rowb + (lane >> 4);
      int colb = ((lane & 15) * 8) ^ ((row & 7) << 3);
      gld_lds16(xb + (size_t)(t0c + row) * CONV_D + DI + g * 128 + colb, &Bsh[d][rowb][0]);
      gld_lds16(xb + (size_t)(t0c + row) * CONV_D + DI + NG * NN + g * 128 + colb, &Csh[d][rowb][0]);
    }
    {
      int s = ptid & 63, pq = ptid >> 6;
      const u16* xr = xb + (size_t)(t0c + s) * CONV_D + g * 512 + r * 64 + p0;
      #pragma unroll
      for (int pb = 0; pb < 2; ++pb) {
        int pl0 = pb * 16 + pq * 4;
        u16x4 v = *(const u16x4*)&xr[pl0];
        #pragma unroll
        for (int j = 0; j < 4; ++j) {
          int p = pl0 + j;
          Xt[d][p][s ^ ((p & 7) << 3)] = v[j];
        }
      }
    }
    {
      int s = ptid & 63, nq = ptid >> 6;
      float wend = __expf(Lsh[t0c + 63] - Lsh[t0c + s]) * dtsh[t0c + s];
      const u16* br = xb + (size_t)(t0c + s) * CONV_D + DI + g * 128;
      #pragma unroll
      for (int nb = 0; nb < 8; ++nb) {
        int n0 = nb * 16 + nq * 4;
        u16x4 v = *(const u16x4*)&br[n0];
        #pragma unroll
        for (int j = 0; j < 4; ++j) {
          int n = n0 + j;
          Btw[d][n][s ^ ((n & 7) << 3)] = f2bf(bf2f(v[j]) * wend);
        }
      }
    }
  };

  if (w >= 4) stage(0, 0);
  __syncthreads();   // P2: chunk 0 staged

  f32x4 hst[2][2];
  #pragma unroll
  for (int i = 0; i < 2; ++i)
    #pragma unroll
    for (int j = 0; j < 2; ++j) hst[i][j] = (f32x4){0.f, 0.f, 0.f, 0.f};

  for (int c = 0; c < NCHUNK; ++c) {
    int d = c & 1;
    int ch = c & 1;
    int t0c = c * 64;
    if (w >= 4) {
      if (c + 1 < NCHUNK) stage(c + 1, d ^ 1);
    } else {
      s16x8 aC[4];
      #pragma unroll
      for (int k = 0; k < 4; ++k)
        aC[k] = *(const s16x8*)&Csh[d][w * 16 + (lane & 15)][(k * 32 + (lane >> 4) * 8) ^ swz];
      f32x4 Gacc[4];
      #pragma unroll
      for (int st = 0; st < 4; ++st) Gacc[st] = (f32x4){0.f, 0.f, 0.f, 0.f};
      #pragma unroll
      for (int st = 0; st < 4; ++st)
        #pragma unroll
        for (int k = 0; k < 4; ++k) {
          s16x8 bB = *(const s16x8*)&Bsh[d][st * 16 + (lane & 15)][(k * 32 + (lane >> 4) * 8) ^ swz];
          Gacc[st] = __builtin_amdgcn_mfma_f32_16x16x32_bf16(aC[k], bB, Gacc[st], 0, 0, 0);
        }
      #pragma unroll
      for (int st = 0; st < 4; ++st) {
        int s = st * 16 + (lane & 15);
        float Ls = Lsh[t0c + s], dts = dtsh[t0c + s];
        #pragma unroll
        for (int j = 0; j < 4; ++j) {
          int t = w * 16 + (lane >> 4) * 4 + j;
          float wgt = (s <= t) ? __expf(Lsh[t0c + t] - Ls) * dts : 0.f;
          GWsh[t][s ^ ((t & 7) << 3)] = f2bf(Gacc[st][j] * wgt);
        }
      }
      f32x4 Yacc[2], Y2acc[2];
      #pragma unroll
      for (int pt = 0; pt < 2; ++pt) { Yacc[pt] = (f32x4){0.f,0.f,0.f,0.f}; Y2acc[pt] = (f32x4){0.f,0.f,0.f,0.f}; }
      s16x8 aGW[2];
      #pragma unroll
      for (int k = 0; k < 2; ++k)
        aGW[k] = *(const s16x8*)&GWsh[w * 16 + (lane & 15)][(k * 32 + (lane >> 4) * 8) ^ swz];
      #pragma unroll
      for (int pt = 0; pt < 2; ++pt) {
        #pragma unroll
        for (int k = 0; k < 2; ++k) {
          s16x8 bX = *(const s16x8*)&Xt[d][pt * 16 + (lane & 15)][(k * 32 + (lane >> 4) * 8) ^ swz];
          Yacc[pt] = __builtin_amdgcn_mfma_f32_16x16x32_bf16(aGW[k], bX, Yacc[pt], 0, 0, 0);
        }
        #pragma unroll
        for (int k = 0; k < 4; ++k) {
          s16x8 bH = *(const s16x8*)&Hbf[ch][pt * 16 + (lane & 15)][(k * 32 + (lane >> 4) * 8) ^ swz];
          Y2acc[pt] = __builtin_amdgcn_mfma_f32_16x16x32_bf16(aC[k], bH, Y2acc[pt], 0, 0, 0);
        }
      }
      float el[4];
      #pragma unroll
      for (int j = 0; j < 4; ++j) el[j] = __expf(Lsh[t0c + w * 16 + (lane >> 4) * 4 + j]);
      #pragma unroll
      for (int pt = 0; pt < 2; ++pt) {
        int p = pt * 16 + (lane & 15);
        #pragma unroll
        for (int j = 0; j < 4; ++j) {
          int t = w * 16 + (lane >> 4) * 4 + j;
          float xv = bf2f(Xt[d][p][t ^ ((p & 7) << 3)]);
          float yv = Yacc[pt][j] + el[j] * Y2acc[pt][j] + Dv * xv;
          y[((size_t)b * LSEQ + t0c + t) * DI + g * 512 + r * 64 + p0 + p] = f2bf(yv);
        }
      }
      float e63 = __expf(Lsh[t0c + 63]);
      s16x8 aX[2][2];
      #pragma unroll
      for (int mp = 0; mp < 2; ++mp)
        #pragma unroll
        for (int k = 0; k < 2; ++k)
          aX[mp][k] = *(const s16x8*)&Xt[d][mp * 16 + (lane & 15)][(k * 32 + (lane >> 4) * 8) ^ swz];
      #pragma unroll
      for (int mp = 0; mp < 2; ++mp)
        #pragma unroll
        for (int nn = 0; nn < 2; ++nn) {
          #pragma unroll
          for (int j = 0; j < 4; ++j) hst[mp][nn][j] *= e63;
          #pragma unroll
          for (int k = 0; k < 2; ++k) {
            s16x8 bW = *(const s16x8*)&Btw[d][w * 32 + nn * 16 + (lane & 15)][(k * 32 + (lane >> 4) * 8) ^ swz];
            hst[mp][nn] = __builtin_amdgcn_mfma_f32_16x16x32_bf16(aX[mp][k], bW, hst[mp][nn], 0, 0, 0);
          }
        }
      #pragma unroll
      for (int mp = 0; mp < 2; ++mp)
        #pragma unroll
        for (int nn = 0; nn < 2; ++nn) {
          int n = w * 32 + nn * 16 + (lane & 15);
          #pragma unroll
          for (int j = 0; j < 4; ++j) {
            int p = mp * 16 + (lane >> 4) * 4 + j;
            Hbf[ch ^ 1][p][n ^ ((p & 7) << 3)] = f2bf(hst[mp][nn][j]);
          }
        }
    }
    __syncthreads();   // single chunk barrier
  }
}

// ---------- y2 = rmsnorm(y * silu(z)) * gw -> bf16 ----------
__global__ __launch_bounds__(256) void gate_kernel(const u16* __restrict__ y, const u16* __restrict__ proj,
        const float* __restrict__ gw, u16* __restrict__ y2) {
  int row = blockIdx.x;
  const u16* yr = y + (size_t)row * DI;
  const u16* zr = proj + (size_t)row * PROJ_P;
  int tid = threadIdx.x;
  f32x4 v[4];
  float s = 0.f;
  #pragma unroll
  for (int i = 0; i < 4; i++) {
    int off = i * 1024 + tid * 4;
    u16x4 av = *(const u16x4*)&yr[off];
    u16x4 zv = *(const u16x4*)&zr[off];
    f32x4 t;
    float z0 = bf2f(zv.x), z1 = bf2f(zv.y), z2 = bf2f(zv.z), z3 = bf2f(zv.w);
    t.x = bf2f(av.x) * (z0 / (1.f + expf(-z0)));
    t.y = bf2f(av.y) * (z1 / (1.f + expf(-z1)));
    t.z = bf2f(av.z) * (z2 / (1.f + expf(-z2)));
    t.w = bf2f(av.w) * (z3 / (1.f + expf(-z3)));
    v[i] = t;
    s += t.x * t.x + t.y * t.y + t.z * t.z + t.w * t.w;
  }
  s = blockReduceSum256(s);
  float rs = rsqrtf(s * (1.f / DI) + 1e-5f);
  #pragma unroll
  for (int i = 0; i < 4; i++) {
    int off = i * 1024 + tid * 4;
    f32x4 wv = *(const f32x4*)&gw[off];
    u16x4 o;
    o.x = f2bf(v[i].x * rs * wv.x);
    o.y = f2bf(v[i].y * rs * wv.y);
    o.z = f2bf(v[i].z * rs * wv.z);
    o.w = f2bf(v[i].w * rs * wv.w);
    *(u16x4*)&y2[(size_t)row * DI + off] = o;
  }
}

extern "C" void kernel_launch(void* const* d_in, const int* in_sizes, int n_in,
                              void* d_out, int out_size, void* d_ws, size_t ws_size,
                              hipStream_t stream) {
  (void)in_sizes; (void)n_in; (void)out_size; (void)ws_size;
  const float* hs      = (const float*)d_in[0];
  const float* res     = (const float*)d_in[1];
  const float* norm_w  = (const float*)d_in[2];
  const float* w_in    = (const float*)d_in[3];
  const float* conv_w  = (const float*)d_in[4];
  const float* conv_b  = (const float*)d_in[5];
  const float* A_log   = (const float*)d_in[6];
  const float* D_param = (const float*)d_in[7];
  const float* dt_bias = (const float*)d_in[8];
  const float* gate_w  = (const float*)d_in[9];
  const float* w_out   = (const float*)d_in[10];

  float* out  = (float*)d_out;
  float* nres = out + (size_t)TOK * DM;

  char* ws = (char*)d_ws;
  size_t off = 0;
  u16*   WB1  = (u16*)(ws + off);   off += (size_t)PROJ_P * DM * 2;
  u16*   WB2  = (u16*)(ws + off);   off += (size_t)DM * DI * 2;
  u16*   XBF  = (u16*)(ws + off);   off += (size_t)TOK * DM * 2;
  u16*   PROJ = (u16*)(ws + off);   off += (size_t)TOK * PROJ_P * 2;
  u16*   XBC  = (u16*)(ws + off);   off += (size_t)TOK * CONV_D * 2;
  float* DTSP = (float*)(ws + off); off += (size_t)TOK * 64 * 4;
  float* DTA  = (float*)(ws + off); off += (size_t)TOK * 64 * 4;
  u16*   Y    = (u16*)(ws + off);   off += (size_t)TOK * DI * 2;
  u16*   Y2   = (u16*)(ws + off);   off += (size_t)TOK * DI * 2;
  u16*   PART = (u16*)(ws + off);   off += (size_t)4 * TOK * DM * 2;

  // both weight conversions in one launch
  cvt2_kernel<<<CVT1_BLOCKS + CVT2_BLOCKS, 256, 0, stream>>>(w_in, WB1, w_out, WB2);
  // residual add + rmsnorm
  addnorm_kernel<<<TOK, 256, 0, stream>>>(hs, res, norm_w, nres, XBF);
  // in_proj GEMM: BK=32 triple-buffered, 2 blocks/CU, column-major map; grid 656 = 8x82
  gemm32<<<(TOK / 128) * (PROJ_P / 256), 512, 0, stream>>>(XBF, WB1, PROJ, DM, PROJ_P, TOK / 128);
  // conv + silu + dt (fused, block-granular)
  conv_dt_kernel<<<CONV_BLOCKS + (TOK * 64) / 256, 256, 0, stream>>>(PROJ, conv_w, conv_b, XBC,
                                                                     dt_bias, A_log, DTSP, DTA);
  // chunked SSD scan, producer/consumer + p-split, 1 barrier/chunk
  ssd_kernel<<<256, 512, 0, stream>>>(XBC, DTSP, DTA, D_param, Y);
  // gated rmsnorm -> bf16
  gate_kernel<<<TOK, 256, 0, stream>>>(Y, PROJ, gate_w, Y2);
  // out_proj GEMM: 8-phase 256^2, K-split 4 -> bf16 partials
  gemm8p<true><<<(TOK / 256) * (DM / 256) * 4, 512, 0, stream>>>(Y2, WB2, PART, DI, DM, DM / 256, 4, (size_t)TOK * DM);
  // sum partials (fp32 accumulate) -> out
  reduce4_kernel<<<(TOK * DM) / 1024, 256, 0, stream>>>(PART, out);
}